// Round 1
// baseline (2031.262 us; speedup 1.0000x reference)
//
#include <hip/hip_runtime.h>
#include <cstddef>
#include <cstdint>

static inline int cdiv_i(int a, int b) { return (a + b - 1) / b; }

// ---- input features: f[i][c] = sum_p voxels[i][p][c] / max(num_points,1); pad row N0 = 0
__global__ void feat_kernel(const float* __restrict__ vox,
                            const int* __restrict__ vnp,
                            float* __restrict__ f, int N0) {
  int t = blockIdx.x * blockDim.x + threadIdx.x;
  if (t >= (N0 + 1) * 4) return;
  int i = t >> 2;
  int c = t & 3;
  if (i >= N0) { f[t] = 0.f; return; }
  const float* v = vox + (size_t)i * 20 + c;
  float s = v[0] + v[4] + v[8] + v[12] + v[16];
  f[t] = s / fmaxf((float)vnp[i], 1.f);
}

// ---- rulebook inversion: tbl[out*K + k] = in  (unique per (out,k); pads have rout==nout)
__global__ void tbl_init_kernel(int* __restrict__ tbl, int n) {
  int t = blockIdx.x * blockDim.x + threadIdx.x;
  if (t < n) tbl[t] = -1;
}

__global__ void tbl_fill_kernel(const int* __restrict__ rin,
                                const int* __restrict__ rout,
                                int* __restrict__ tbl, int K, int R, int nout) {
  int e = blockIdx.x * blockDim.x + threadIdx.x;
  if (e >= K * R) return;
  int o = rout[e];
  if ((unsigned)o >= (unsigned)nout) return;  // pad entries target row nout
  int k = e / R;
  tbl[(size_t)o * K + k] = rin[e];
}

// ---- gather conv + fused BN/ReLU. thread = (row group of RPT rows, channel c).
// Invalid table entries -> input pad row (zeros). Row nout of output zeroed here too.
template <int K, int Ci, int Co, int RPT, bool UNI>
__global__ __launch_bounds__(256) void conv_gather(
    const float* __restrict__ feat, const float* __restrict__ W,
    const int* __restrict__ tbl, const float* __restrict__ sc,
    const float* __restrict__ bi, float* __restrict__ out, int nout, int nin) {
  int t = blockIdx.x * blockDim.x + threadIdx.x;
  int c = t % Co;
  int i0 = (t / Co) * RPT;
  if (i0 > nout) return;
  float acc[RPT];
#pragma unroll
  for (int r = 0; r < RPT; ++r) acc[r] = 0.f;

  for (int k = 0; k < K; ++k) {
    int j[RPT];
#pragma unroll
    for (int r = 0; r < RPT; ++r) {
      int i = i0 + r;
      int jj = (i < nout) ? tbl[(size_t)i * K + k] : -1;
      jj = (jj < 0) ? nin : jj;            // pad row = zeros -> branchless
      if (UNI) jj = __builtin_amdgcn_readfirstlane(jj);  // Co>=64: wave-uniform
      j[r] = jj;
    }
    const float* Wk = W + ((size_t)k * Ci) * Co + c;
#pragma unroll
    for (int c4 = 0; c4 < Ci / 4; ++c4) {
      float4 fv[RPT];
#pragma unroll
      for (int r = 0; r < RPT; ++r)
        fv[r] = *(const float4*)(feat + (size_t)j[r] * Ci + c4 * 4);
#pragma unroll
      for (int q = 0; q < 4; ++q) {
        float w = Wk[(size_t)(c4 * 4 + q) * Co];
#pragma unroll
        for (int r = 0; r < RPT; ++r) {
          float fq = (q == 0) ? fv[r].x : (q == 1) ? fv[r].y
                   : (q == 2) ? fv[r].z : fv[r].w;
          acc[r] = fmaf(fq, w, acc[r]);
        }
      }
    }
  }
  float s = sc[c], bb = bi[c];
#pragma unroll
  for (int r = 0; r < RPT; ++r) {
    int i = i0 + r;
    if (i < nout)
      out[(size_t)i * Co + c] = fmaxf(fmaf(acc[r], s, bb), 0.f);
    else if (i == nout)
      out[(size_t)i * Co + c] = 0.f;       // zero pad row for next layer's gather
  }
}

__global__ void zero_kernel(float* __restrict__ p, int n) {
  int t = blockIdx.x * blockDim.x + threadIdx.x;
  if (t < n) p[t] = 0.f;
}

// all x >= 0 (post-ReLU) so int-compare atomicMax == float max; out pre-zeroed
__global__ void segmax_kernel(const float* __restrict__ x,
                              const int* __restrict__ batch, int n,
                              float* __restrict__ out) {
  int t = blockIdx.x * blockDim.x + threadIdx.x;
  if (t >= n * 128) return;
  int i = t >> 7;
  int c = t & 127;
  atomicMax((int*)out + ((size_t)batch[i] << 7) + c, __float_as_int(x[t]));
}

extern "C" void kernel_launch(void* const* d_in, const int* in_sizes, int n_in,
                              void* d_out, int out_size, void* d_ws, size_t ws_size,
                              hipStream_t stream) {
  auto I = [&](int idx) { return (const int*)d_in[idx]; };
  auto F = [&](int idx) { return (const float*)d_in[idx]; };

  const int N0  = in_sizes[1];
  const int R1  = in_sizes[3] / 27;
  const int R2s = in_sizes[5] / 27;
  const int n2  = in_sizes[7];
  const int R2  = in_sizes[8] / 27;
  const int R3s = in_sizes[10] / 27;
  const int n3  = in_sizes[12];
  const int R3  = in_sizes[13] / 27;
  const int R4s = in_sizes[15] / 27;
  const int n4  = in_sizes[17];
  const int R4  = in_sizes[18] / 27;
  const int Ro  = in_sizes[20] / 3;
  const int no  = in_sizes[22];

  // ws layout (4-byte elements): f0 | bufA | bufB | tbl
  float* ws = (float*)d_ws;
  size_t off = 0;
  float* f0 = ws + off; off += (size_t)(N0 + 1) * 4;
  size_t S = (size_t)(N0 + 1) * 16;
  auto smax = [&](size_t v) { if (v > S) S = v; };
  smax((size_t)(n2 + 1) * 32);
  smax((size_t)(n3 + 1) * 64);
  smax((size_t)(n4 + 1) * 64);
  smax((size_t)(no + 1) * 128);
  S = (S + 3) & ~(size_t)3;
  float* bufA = ws + off; off += S;
  float* bufB = ws + off; off += S;
  int* tbl = (int*)(ws + off);

  feat_kernel<<<cdiv_i((N0 + 1) * 4, 256), 256, 0, stream>>>(F(0), I(1), f0, N0);

  auto build = [&](const int* rin, const int* rout, int K, int R, int nout) {
    tbl_init_kernel<<<cdiv_i(nout * K, 256), 256, 0, stream>>>(tbl, nout * K);
    tbl_fill_kernel<<<cdiv_i(K * R, 256), 256, 0, stream>>>(rin, rout, tbl, K, R, nout);
  };

#define CONV(Kk, CI, CO, UNIv, IN, WI, OUTB, NOUT, NIN)                          \
  do {                                                                           \
    int groups = cdiv_i((NOUT) + 1, 4);                                          \
    int threads = groups * (CO);                                                 \
    conv_gather<Kk, CI, CO, 4, UNIv>                                             \
        <<<cdiv_i(threads, 256), 256, 0, stream>>>(                              \
            IN, F(WI), tbl, F((WI) + 1), F((WI) + 2), OUTB, NOUT, NIN);          \
  } while (0)

  // stage 1 (subm rb1, shared table for conv_in + conv1)
  build(I(3), I(4), 27, R1, N0);
  CONV(27, 4, 16, false, f0, 23, bufA, N0, N0);    // conv_in
  CONV(27, 16, 16, false, bufA, 26, bufB, N0, N0); // conv1
  // stage 2
  build(I(5), I(6), 27, R2s, n2);
  CONV(27, 16, 32, false, bufB, 29, bufA, n2, N0); // conv2a (stride)
  build(I(8), I(9), 27, R2, n2);
  CONV(27, 32, 32, false, bufA, 32, bufB, n2, n2); // conv2b
  CONV(27, 32, 32, false, bufB, 35, bufA, n2, n2); // conv2c
  // stage 3
  build(I(10), I(11), 27, R3s, n3);
  CONV(27, 32, 64, true, bufA, 38, bufB, n3, n2);  // conv3a (stride)
  build(I(13), I(14), 27, R3, n3);
  CONV(27, 64, 64, true, bufB, 41, bufA, n3, n3);  // conv3b
  CONV(27, 64, 64, true, bufA, 44, bufB, n3, n3);  // conv3c
  // stage 4
  build(I(15), I(16), 27, R4s, n4);
  CONV(27, 64, 64, true, bufB, 47, bufA, n4, n3);  // conv4a (stride)
  build(I(18), I(19), 27, R4, n4);
  CONV(27, 64, 64, true, bufA, 50, bufB, n4, n4);  // conv4b
  CONV(27, 64, 64, true, bufB, 53, bufA, n4, n4);  // conv4c
  // out conv (K=3)
  build(I(20), I(21), 3, Ro, no);
  CONV(3, 64, 128, true, bufA, 56, bufB, no, n4);  // conv_out

  zero_kernel<<<cdiv_i(out_size, 256), 256, 0, stream>>>((float*)d_out, out_size);
  segmax_kernel<<<cdiv_i(no * 128, 256), 256, 0, stream>>>(bufB, I(22), no,
                                                           (float*)d_out);
#undef CONV
}

// Round 2
// 689.579 us; speedup vs baseline: 2.9457x; 2.9457x over previous
//
#include <hip/hip_runtime.h>
#include <cstddef>
#include <cstdint>

typedef _Float16 half8 __attribute__((ext_vector_type(8)));
typedef float floatx4 __attribute__((ext_vector_type(4)));

static inline int cdiv_i(int a, int b) { return (a + b - 1) / b; }

// ---- input features (f16, padded Ci=8): f[i][c] = sum_p vox[i][p][c]/max(np,1)
__global__ void feat_kernel(const float* __restrict__ vox,
                            const int* __restrict__ vnp,
                            _Float16* __restrict__ f, int N0) {
  int t = blockIdx.x * blockDim.x + threadIdx.x;
  if (t >= (N0 + 1) * 8) return;
  int i = t >> 3, c = t & 7;
  float v = 0.f;
  if (i < N0 && c < 4) {
    const float* p = vox + (size_t)i * 20 + c;
    v = (p[0] + p[4] + p[8] + p[12] + p[16]) / fmaxf((float)vnp[i], 1.f);
  }
  f[t] = (_Float16)v;
}

// ---- rulebook inversion fill (table pre-memset to -1)
__global__ void tbl_fill_kernel(const int* __restrict__ rin,
                                const int* __restrict__ rout,
                                int* __restrict__ tbl, int K, int R, int nout) {
  int e = blockIdx.x * blockDim.x + threadIdx.x;
  if (e >= K * R) return;
  int o = rout[e];
  if ((unsigned)o >= (unsigned)nout) return;
  int k = e / R;
  tbl[(size_t)o * K + k] = rin[e];
}

// ---- fused weight pack: fp32 W[k][ci][co] -> f16 B-fragment panels.
// element e of layer l: e = ((ch*NT + t)*64 + lane)*8 + j ;
// kk = ch*32 + (lane>>4)*8 + j ; k = kk/CiPad ; ci = kk%CiPad ; n = t*16+(lane&15)
struct WP { const float* W; int K, Ci, CiPad, Co, start, end, off; };
struct WPs { WP d[12]; };
__global__ void wpack_all(WPs P, _Float16* __restrict__ Bp, int total) {
  int idx = blockIdx.x * blockDim.x + threadIdx.x;
  if (idx >= total) return;
#pragma unroll
  for (int l = 0; l < 12; ++l) {
    if (idx >= P.d[l].start && idx < P.d[l].end) {
      const WP w = P.d[l];
      int e = idx - w.start;
      int j = e & 7;
      int lane = (e >> 3) & 63;
      int rest = e >> 9;
      int NT = w.Co >> 4;
      int t = rest % NT, ch = rest / NT;
      int kk = ch * 32 + ((lane >> 4) << 3) + j;
      int k = kk / w.CiPad, ci = kk % w.CiPad;
      int n = t * 16 + (lane & 15);
      float v = (k < w.K && ci < w.Ci)
                    ? w.W[((size_t)k * w.Ci + ci) * w.Co + n]
                    : 0.f;
      Bp[w.off + e] = (_Float16)v;
    }
  }
}

// ---- gather-GEMM conv via MFMA 16x16x32 f16, fp32 accum, fused BN+ReLU
template <int K, int CiPad, int Co, int T>
__global__ __launch_bounds__(256) void conv_mfma(
    const _Float16* __restrict__ feat, const _Float16* __restrict__ Bp,
    const int* __restrict__ tbl, const float* __restrict__ sc,
    const float* __restrict__ bi, _Float16* __restrict__ out,
    int nout, int nin) {
  constexpr int NT = Co / 16;
  constexpr int NCH = (K * CiPad + 31) / 32;
  constexpr int L2C = (CiPad == 8) ? 3 : (CiPad == 16) ? 4 : (CiPad == 32) ? 5 : 6;
  if (blockIdx.x == 0 && threadIdx.x < Co)
    out[(size_t)nout * Co + threadIdx.x] = (_Float16)0.f;  // zero pad row
  const int wave = threadIdx.x >> 6, lane = threadIdx.x & 63;
  const int m = lane & 15;
  const int lb = (lane >> 4) * 8;
  const int i0 = (blockIdx.x * 4 + wave) * (16 * T);
  if (i0 >= nout) return;

  floatx4 acc[T][NT];
#pragma unroll
  for (int t = 0; t < T; ++t)
#pragma unroll
    for (int n = 0; n < NT; ++n) {
      floatx4 z = {0.f, 0.f, 0.f, 0.f};
      acc[t][n] = z;
    }
  int rows[T];
#pragma unroll
  for (int t = 0; t < T; ++t) rows[t] = i0 + t * 16 + m;

  if constexpr (CiPad >= 32) {
    constexpr int SUB = CiPad / 32;
    for (int k = 0; k < K; ++k) {
      int j[T];
#pragma unroll
      for (int t = 0; t < T; ++t) {
        int jj = (rows[t] < nout) ? tbl[(size_t)rows[t] * K + k] : -1;
        j[t] = (jj < 0) ? nin : jj;
      }
#pragma unroll
      for (int s = 0; s < SUB; ++s) {
        half8 a[T];
#pragma unroll
        for (int t = 0; t < T; ++t)
          a[t] = *(const half8*)(feat + (size_t)j[t] * CiPad + s * 32 + lb);
        const _Float16* bp = Bp + ((size_t)(k * SUB + s) * NT * 64 + lane) * 8;
#pragma unroll
        for (int n = 0; n < NT; ++n) {
          half8 b = *(const half8*)(bp + n * 512);
#pragma unroll
          for (int t = 0; t < T; ++t)
            acc[t][n] =
                __builtin_amdgcn_mfma_f32_16x16x32_f16(a[t], b, acc[t][n], 0, 0, 0);
        }
      }
    }
  } else {
    for (int ch = 0; ch < NCH; ++ch) {
      int kk = ch * 32 + lb;
      int ko = kk >> L2C;
      int ci0 = kk & (CiPad - 1);
      int j[T];
#pragma unroll
      for (int t = 0; t < T; ++t) {
        int jj = (rows[t] < nout && ko < K) ? tbl[(size_t)rows[t] * K + ko] : -1;
        j[t] = (jj < 0) ? nin : jj;
      }
      half8 a[T];
#pragma unroll
      for (int t = 0; t < T; ++t)
        a[t] = *(const half8*)(feat + (size_t)j[t] * CiPad + ci0);
      const _Float16* bp = Bp + ((size_t)ch * NT * 64 + lane) * 8;
#pragma unroll
      for (int n = 0; n < NT; ++n) {
        half8 b = *(const half8*)(bp + n * 512);
#pragma unroll
        for (int t = 0; t < T; ++t)
          acc[t][n] =
              __builtin_amdgcn_mfma_f32_16x16x32_f16(a[t], b, acc[t][n], 0, 0, 0);
      }
    }
  }

  // epilogue: C/D layout col=lane&15, row=(lane>>4)*4+reg
#pragma unroll
  for (int n = 0; n < NT; ++n) {
    int col = n * 16 + m;
    float s_ = sc[col], b_ = bi[col];
#pragma unroll
    for (int t = 0; t < T; ++t) {
#pragma unroll
      for (int r = 0; r < 4; ++r) {
        int orow = i0 + t * 16 + (lane >> 4) * 4 + r;
        if (orow < nout) {
          float v = fmaxf(fmaf(acc[t][n][r], s_, b_), 0.f);
          out[(size_t)orow * Co + col] = (_Float16)v;
        }
      }
    }
  }
}

// values >= 0 post-ReLU -> int atomicMax == float max; out pre-zeroed
__global__ void segmax_kernel(const _Float16* __restrict__ x,
                              const int* __restrict__ batch, int n,
                              float* __restrict__ out) {
  int t = blockIdx.x * blockDim.x + threadIdx.x;
  if (t >= n * 128) return;
  int i = t >> 7, c = t & 127;
  float v = (float)x[t];
  atomicMax((int*)out + ((size_t)batch[i] << 7) + c, __float_as_int(v));
}

extern "C" void kernel_launch(void* const* d_in, const int* in_sizes, int n_in,
                              void* d_out, int out_size, void* d_ws, size_t ws_size,
                              hipStream_t stream) {
  auto I = [&](int idx) { return (const int*)d_in[idx]; };
  auto F = [&](int idx) { return (const float*)d_in[idx]; };

  const int N0  = in_sizes[1];
  const int R1  = in_sizes[3] / 27;
  const int R2s = in_sizes[5] / 27;
  const int n2  = in_sizes[7];
  const int R2  = in_sizes[8] / 27;
  const int R3s = in_sizes[10] / 27;
  const int n3  = in_sizes[12];
  const int R3  = in_sizes[13] / 27;
  const int R4s = in_sizes[15] / 27;
  const int n4  = in_sizes[17];
  const int R4  = in_sizes[18] / 27;
  const int Ro  = in_sizes[20] / 3;
  const int no  = in_sizes[22];

  // ---- weight pack descriptors (12 layers)
  const int wIdx[12] = {23, 26, 29, 32, 35, 38, 41, 44, 47, 50, 53, 56};
  const int Ks[12]   = {27, 27, 27, 27, 27, 27, 27, 27, 27, 27, 27, 3};
  const int Cis[12]  = {4, 16, 16, 32, 32, 32, 64, 64, 64, 64, 64, 64};
  const int Cos[12]  = {16, 16, 32, 32, 32, 64, 64, 64, 64, 64, 64, 128};
  WPs P;
  int wtot = 0;
  int bpOff[12];
  for (int l = 0; l < 12; ++l) {
    int cip = Cis[l] < 8 ? 8 : Cis[l];
    int nch = (Ks[l] * cip + 31) / 32;
    int nt = Cos[l] / 16;
    int sz = nch * nt * 512;
    P.d[l].W = F(wIdx[l]);
    P.d[l].K = Ks[l];
    P.d[l].Ci = Cis[l];
    P.d[l].CiPad = cip;
    P.d[l].Co = Cos[l];
    P.d[l].start = wtot;
    P.d[l].end = wtot + sz;
    P.d[l].off = wtot;
    bpOff[l] = wtot;
    wtot += sz;
  }

  // ---- workspace layout (halves, 16B aligned chunks)
  size_t S = (size_t)(N0 + 1) * 16;
  auto smax = [&](size_t v) { if (v > S) S = v; };
  smax((size_t)(n2 + 1) * 32);
  smax((size_t)(n3 + 1) * 64);
  smax((size_t)(n4 + 1) * 64);
  smax((size_t)(no + 1) * 128);
  S = (S + 7) & ~(size_t)7;

  _Float16* h = (_Float16*)d_ws;
  size_t off = 0;
  _Float16* f0 = h + off;   off += (size_t)(N0 + 1) * 8;
  _Float16* bufA = h + off; off += S;
  _Float16* bufB = h + off; off += S;
  _Float16* Bp = h + off;   off += (size_t)((wtot + 7) & ~7);
  int* tbl = (int*)(h + off);

  // ---- prep
  feat_kernel<<<cdiv_i((N0 + 1) * 8, 256), 256, 0, stream>>>(F(0), I(1), f0, N0);
  wpack_all<<<cdiv_i(wtot, 256), 256, 0, stream>>>(P, Bp, wtot);

  auto build = [&](const int* rin, const int* rout, int K, int R, int nout) {
    hipMemsetAsync(tbl, 0xFF, (size_t)nout * K * 4, stream);
    tbl_fill_kernel<<<cdiv_i(K * R, 256), 256, 0, stream>>>(rin, rout, tbl, K, R, nout);
  };

#define CONV(Kk, CIP, CO, Tt, IN, LI, OUTB, NOUT, NIN)                       \
  conv_mfma<Kk, CIP, CO, Tt><<<cdiv_i(NOUT, 64 * Tt), 256, 0, stream>>>(     \
      IN, Bp + bpOff[LI], tbl, F(wIdx[LI] + 1), F(wIdx[LI] + 2), OUTB, NOUT, NIN)

  // stage 1
  build(I(3), I(4), 27, R1, N0);
  CONV(27, 8, 16, 1, f0, 0, bufA, N0, N0);     // conv_in
  CONV(27, 16, 16, 1, bufA, 1, bufB, N0, N0);  // conv1
  // stage 2
  build(I(5), I(6), 27, R2s, n2);
  CONV(27, 16, 32, 1, bufB, 2, bufA, n2, N0);  // conv2a
  build(I(8), I(9), 27, R2, n2);
  CONV(27, 32, 32, 2, bufA, 3, bufB, n2, n2);  // conv2b
  CONV(27, 32, 32, 2, bufB, 4, bufA, n2, n2);  // conv2c
  // stage 3
  build(I(10), I(11), 27, R3s, n3);
  CONV(27, 32, 64, 2, bufA, 5, bufB, n3, n2);  // conv3a
  build(I(13), I(14), 27, R3, n3);
  CONV(27, 64, 64, 2, bufB, 6, bufA, n3, n3);  // conv3b
  CONV(27, 64, 64, 2, bufA, 7, bufB, n3, n3);  // conv3c
  // stage 4
  build(I(15), I(16), 27, R4s, n4);
  CONV(27, 64, 64, 1, bufB, 8, bufA, n4, n3);  // conv4a
  build(I(18), I(19), 27, R4, n4);
  CONV(27, 64, 64, 1, bufA, 9, bufB, n4, n4);  // conv4b
  CONV(27, 64, 64, 1, bufB, 10, bufA, n4, n4); // conv4c
  // out conv
  build(I(20), I(21), 3, Ro, no);
  CONV(3, 64, 128, 1, bufA, 11, bufB, no, n4); // conv_out

  hipMemsetAsync(d_out, 0, (size_t)out_size * 4, stream);
  segmax_kernel<<<cdiv_i(no * 128, 256), 256, 0, stream>>>(bufB, I(22), no,
                                                           (float*)d_out);
#undef CONV
}

// Round 3
// 580.930 us; speedup vs baseline: 3.4966x; 1.1870x over previous
//
#include <hip/hip_runtime.h>
#include <cstddef>
#include <cstdint>

typedef _Float16 half8 __attribute__((ext_vector_type(8)));
typedef float floatx4 __attribute__((ext_vector_type(4)));

static inline int cdiv_i(int a, int b) { return (a + b - 1) / b; }

// ---- input features (f16, padded Ci=8): f[i][c] = sum_p vox[i][p][c]/max(np,1)
__global__ void feat_kernel(const float* __restrict__ vox,
                            const int* __restrict__ vnp,
                            _Float16* __restrict__ f, int N0) {
  int t = blockIdx.x * blockDim.x + threadIdx.x;
  if (t >= (N0 + 1) * 8) return;
  int i = t >> 3, c = t & 7;
  float v = 0.f;
  if (i < N0 && c < 4) {
    const float* p = vox + (size_t)i * 20 + c;
    v = (p[0] + p[4] + p[8] + p[12] + p[16]) / fmaxf((float)vnp[i], 1.f);
  }
  f[t] = (_Float16)v;
}

// ---- fused rulebook inversion over all 8 rulebooks (tables pre-memset to -1)
struct RB { const int* rin; const int* rout; int K, R, nout, start, end, off; };
struct RBs { RB d[8]; };
__global__ void rb_fill_all(RBs P, int* __restrict__ tbl, int total) {
  int idx = blockIdx.x * blockDim.x + threadIdx.x;
  if (idx >= total) return;
#pragma unroll
  for (int l = 0; l < 8; ++l) {
    if (idx >= P.d[l].start && idx < P.d[l].end) {
      const RB rb = P.d[l];
      int e = idx - rb.start;
      int o = rb.rout[e];
      if ((unsigned)o < (unsigned)rb.nout) {
        int k = e / rb.R;
        tbl[rb.off + (size_t)o * rb.K + k] = rb.rin[e];
      }
    }
  }
}

// single-rulebook fill (fallback path when ws is tight)
__global__ void tbl_fill_kernel(const int* __restrict__ rin,
                                const int* __restrict__ rout,
                                int* __restrict__ tbl, int K, int R, int nout) {
  int e = blockIdx.x * blockDim.x + threadIdx.x;
  if (e >= K * R) return;
  int o = rout[e];
  if ((unsigned)o >= (unsigned)nout) return;
  int k = e / R;
  tbl[(size_t)o * K + k] = rin[e];
}

// ---- fused weight pack: fp32 W[k][ci][co] -> f16 B-fragment panels.
struct WP { const float* W; int K, Ci, CiPad, Co, start, end, off; };
struct WPs { WP d[12]; };
__global__ void wpack_all(WPs P, _Float16* __restrict__ Bp, int total) {
  int idx = blockIdx.x * blockDim.x + threadIdx.x;
  if (idx >= total) return;
#pragma unroll
  for (int l = 0; l < 12; ++l) {
    if (idx >= P.d[l].start && idx < P.d[l].end) {
      const WP w = P.d[l];
      int e = idx - w.start;
      int j = e & 7;
      int lane = (e >> 3) & 63;
      int rest = e >> 9;
      int NT = w.Co >> 4;
      int t = rest % NT, ch = rest / NT;
      int kk = ch * 32 + ((lane >> 4) << 3) + j;
      int k = kk / w.CiPad, ci = kk % w.CiPad;
      int n = t * 16 + (lane & 15);
      float v = (k < w.K && ci < w.Ci)
                    ? w.W[((size_t)k * w.Ci + ci) * w.Co + n]
                    : 0.f;
      Bp[w.off + e] = (_Float16)v;
    }
  }
}

// ---- gather-GEMM conv via MFMA 16x16x32 f16, fp32 accum, fused BN+ReLU
// NTW = 16-col tiles per wave; waves split remaining tiles (colG) then rows.
template <int K, int CiPad, int Co, int T, int NTW>
__global__ __launch_bounds__(256) void conv_mfma(
    const _Float16* __restrict__ feat, const _Float16* __restrict__ Bp,
    const int* __restrict__ tbl, const float* __restrict__ sc,
    const float* __restrict__ bi, _Float16* __restrict__ out,
    int nout, int nin) {
  constexpr int NT = Co / 16;
  constexpr int colG = NT / NTW;       // waves along columns
  constexpr int rowG = 4 / colG;       // waves along rows
  static_assert(4 % colG == 0, "colG must divide 4");
  constexpr int NCH = (K * CiPad + 31) / 32;
  constexpr int L2C = (CiPad == 8) ? 3 : (CiPad == 16) ? 4 : (CiPad == 32) ? 5 : 6;
  if (blockIdx.x == 0 && threadIdx.x < Co)
    out[(size_t)nout * Co + threadIdx.x] = (_Float16)0.f;  // zero pad row
  const int wave = threadIdx.x >> 6, lane = threadIdx.x & 63;
  const int rowg = wave / colG, colg = wave % colG;
  const int m = lane & 15;
  const int lb = (lane >> 4) * 8;
  const int i0 = (blockIdx.x * rowG + rowg) * (16 * T);
  if (i0 >= nout) return;

  floatx4 acc[T][NTW];
#pragma unroll
  for (int t = 0; t < T; ++t)
#pragma unroll
    for (int n = 0; n < NTW; ++n) {
      floatx4 z = {0.f, 0.f, 0.f, 0.f};
      acc[t][n] = z;
    }
  int rows[T];
#pragma unroll
  for (int t = 0; t < T; ++t) rows[t] = i0 + t * 16 + m;

  if constexpr (CiPad >= 32) {
    constexpr int SUB = CiPad / 32;
    for (int k = 0; k < K; ++k) {
      int j[T];
#pragma unroll
      for (int t = 0; t < T; ++t) {
        int jj = (rows[t] < nout) ? tbl[(size_t)rows[t] * K + k] : -1;
        j[t] = (jj < 0) ? nin : jj;
      }
#pragma unroll
      for (int s = 0; s < SUB; ++s) {
        half8 a[T];
#pragma unroll
        for (int t = 0; t < T; ++t)
          a[t] = *(const half8*)(feat + (size_t)j[t] * CiPad + s * 32 + lb);
        const _Float16* bp = Bp + ((size_t)(k * SUB + s) * NT * 64 + lane) * 8;
#pragma unroll
        for (int n = 0; n < NTW; ++n) {
          half8 b = *(const half8*)(bp + (colg * NTW + n) * 512);
#pragma unroll
          for (int t = 0; t < T; ++t)
            acc[t][n] =
                __builtin_amdgcn_mfma_f32_16x16x32_f16(a[t], b, acc[t][n], 0, 0, 0);
        }
      }
    }
  } else {
    for (int ch = 0; ch < NCH; ++ch) {
      int kk = ch * 32 + lb;
      int ko = kk >> L2C;
      int ci0 = kk & (CiPad - 1);
      int j[T];
#pragma unroll
      for (int t = 0; t < T; ++t) {
        int jj = (rows[t] < nout && ko < K) ? tbl[(size_t)rows[t] * K + ko] : -1;
        j[t] = (jj < 0) ? nin : jj;
      }
      half8 a[T];
#pragma unroll
      for (int t = 0; t < T; ++t)
        a[t] = *(const half8*)(feat + (size_t)j[t] * CiPad + ci0);
      const _Float16* bp = Bp + ((size_t)ch * NT * 64 + lane) * 8;
#pragma unroll
      for (int n = 0; n < NTW; ++n) {
        half8 b = *(const half8*)(bp + (colg * NTW + n) * 512);
#pragma unroll
        for (int t = 0; t < T; ++t)
          acc[t][n] =
              __builtin_amdgcn_mfma_f32_16x16x32_f16(a[t], b, acc[t][n], 0, 0, 0);
      }
    }
  }

  // epilogue: C/D layout col=lane&15, row=(lane>>4)*4+reg
#pragma unroll
  for (int n = 0; n < NTW; ++n) {
    int col = (colg * NTW + n) * 16 + m;
    float s_ = sc[col], b_ = bi[col];
#pragma unroll
    for (int t = 0; t < T; ++t) {
#pragma unroll
      for (int r = 0; r < 4; ++r) {
        int orow = i0 + t * 16 + (lane >> 4) * 4 + r;
        if (orow < nout) {
          float v = fmaxf(fmaf(acc[t][n][r], s_, b_), 0.f);
          out[(size_t)orow * Co + col] = (_Float16)v;
        }
      }
    }
  }
}

// ---- two-stage segment max; batch_out is nondecreasing (coords sorted by key).
// Each thread scans a row range for one channel, flushing one atomic per batch run.
__global__ __launch_bounds__(256) void segmax2(const _Float16* __restrict__ x,
                                               const int* __restrict__ batch,
                                               int n, float* __restrict__ out) {
  const int RPB = 128;
  int c = threadIdx.x & 127, g = threadIdx.x >> 7;
  int r0 = blockIdx.x * RPB + g;
  int rend = min(n, blockIdx.x * RPB + RPB);
  float mx = 0.f;
  int cb = -1;
  for (int r = r0; r < rend; r += 2) {
    int b = batch[r];
    if (b != cb) {
      if (cb >= 0)
        atomicMax((int*)out + ((size_t)cb << 7) + c, __float_as_int(mx));
      cb = b;
      mx = 0.f;
    }
    mx = fmaxf(mx, (float)x[(size_t)r * 128 + c]);
  }
  if (cb >= 0)
    atomicMax((int*)out + ((size_t)cb << 7) + c, __float_as_int(mx));
}

extern "C" void kernel_launch(void* const* d_in, const int* in_sizes, int n_in,
                              void* d_out, int out_size, void* d_ws, size_t ws_size,
                              hipStream_t stream) {
  auto I = [&](int idx) { return (const int*)d_in[idx]; };
  auto F = [&](int idx) { return (const float*)d_in[idx]; };

  const int N0  = in_sizes[1];
  const int R1  = in_sizes[3] / 27;
  const int R2s = in_sizes[5] / 27;
  const int n2  = in_sizes[7];
  const int R2  = in_sizes[8] / 27;
  const int R3s = in_sizes[10] / 27;
  const int n3  = in_sizes[12];
  const int R3  = in_sizes[13] / 27;
  const int R4s = in_sizes[15] / 27;
  const int n4  = in_sizes[17];
  const int R4  = in_sizes[18] / 27;
  const int Ro  = in_sizes[20] / 3;
  const int no  = in_sizes[22];

  // ---- weight pack descriptors (12 layers)
  const int wIdx[12] = {23, 26, 29, 32, 35, 38, 41, 44, 47, 50, 53, 56};
  const int Ks[12]   = {27, 27, 27, 27, 27, 27, 27, 27, 27, 27, 27, 3};
  const int Cis[12]  = {4, 16, 16, 32, 32, 32, 64, 64, 64, 64, 64, 64};
  const int Cos[12]  = {16, 16, 32, 32, 32, 64, 64, 64, 64, 64, 64, 128};
  WPs P;
  int wtot = 0;
  int bpOff[12];
  for (int l = 0; l < 12; ++l) {
    int cip = Cis[l] < 8 ? 8 : Cis[l];
    int nch = (Ks[l] * cip + 31) / 32;
    int nt = Cos[l] / 16;
    int sz = nch * nt * 512;
    P.d[l].W = F(wIdx[l]);
    P.d[l].K = Ks[l];  P.d[l].Ci = Cis[l];  P.d[l].CiPad = cip;  P.d[l].Co = Cos[l];
    P.d[l].start = wtot;  P.d[l].end = wtot + sz;  P.d[l].off = wtot;
    bpOff[l] = wtot;
    wtot += sz;
  }

  // ---- rulebook descriptors (8 tables)
  RBs RP;
  const int rbRin[8]  = {3, 5, 8, 10, 13, 15, 18, 20};
  const int rbRs[8]   = {R1, R2s, R2, R3s, R3, R4s, R4, Ro};
  const int rbKs[8]   = {27, 27, 27, 27, 27, 27, 27, 3};
  const int rbNout[8] = {N0, n2, n2, n3, n3, n4, n4, no};
  size_t tblInts[8];
  size_t tblOff[8];
  size_t totTbl = 0, maxTbl = 0;
  int totFill = 0;
  for (int l = 0; l < 8; ++l) {
    tblInts[l] = (size_t)rbNout[l] * rbKs[l];
    tblOff[l] = totTbl;
    totTbl += tblInts[l];
    if (tblInts[l] > maxTbl) maxTbl = tblInts[l];
    RP.d[l].rin = I(rbRin[l]);
    RP.d[l].rout = I(rbRin[l] + 1);
    RP.d[l].K = rbKs[l];  RP.d[l].R = rbRs[l];  RP.d[l].nout = rbNout[l];
    RP.d[l].start = totFill;
    totFill += rbKs[l] * rbRs[l];
    RP.d[l].end = totFill;
    RP.d[l].off = (int)tblOff[l];
  }

  // ---- workspace layout (halves)
  size_t S = (size_t)(N0 + 1) * 16;
  auto smax = [&](size_t v) { if (v > S) S = v; };
  smax((size_t)(n2 + 1) * 32);
  smax((size_t)(n3 + 1) * 64);
  smax((size_t)(n4 + 1) * 64);
  smax((size_t)(no + 1) * 128);
  S = (S + 7) & ~(size_t)7;

  _Float16* h = (_Float16*)d_ws;
  size_t off = 0;
  _Float16* f0 = h + off;   off += (size_t)(N0 + 1) * 8;
  _Float16* bufA = h + off; off += S;
  _Float16* bufB = h + off; off += S;
  _Float16* Bp = h + off;   off += (size_t)((wtot + 7) & ~7);
  int* tblBase = (int*)(h + off);
  size_t usedBytes = off * 2;
  bool prebuilt = (usedBytes + totTbl * 4 <= ws_size);

  // ---- prep (independent of conv chain)
  feat_kernel<<<cdiv_i((N0 + 1) * 8, 256), 256, 0, stream>>>(F(0), I(1), f0, N0);
  wpack_all<<<cdiv_i(wtot, 256), 256, 0, stream>>>(P, Bp, wtot);
  hipMemsetAsync(d_out, 0, (size_t)out_size * 4, stream);

  // conv-layer -> rulebook mapping
  const int l2rb[12] = {0, 0, 1, 2, 2, 3, 4, 4, 5, 6, 6, 7};
  const int* tblL[12];
  if (prebuilt) {
    hipMemsetAsync(tblBase, 0xFF, totTbl * 4, stream);
    rb_fill_all<<<cdiv_i(totFill, 256), 256, 0, stream>>>(RP, tblBase, totFill);
    for (int l = 0; l < 12; ++l) tblL[l] = tblBase + tblOff[l2rb[l]];
  } else {
    for (int l = 0; l < 12; ++l) tblL[l] = tblBase;  // rebuilt sequentially
  }
  auto buildSeq = [&](int rb) {
    if (prebuilt) return;
    hipMemsetAsync(tblBase, 0xFF, tblInts[rb] * 4, stream);
    tbl_fill_kernel<<<cdiv_i(rbKs[rb] * rbRs[rb], 256), 256, 0, stream>>>(
        I(rbRin[rb]), I(rbRin[rb] + 1), tblBase, rbKs[rb], rbRs[rb], rbNout[rb]);
  };

#define CONV(Kk, CIP, CO, Tt, NTWv, IN, LI, OUTB, NOUT, NIN)                  \
  do {                                                                        \
    constexpr int rowsPerBlk = (4 / ((CO / 16) / NTWv)) * 16 * Tt;            \
    conv_mfma<Kk, CIP, CO, Tt, NTWv>                                          \
        <<<cdiv_i(NOUT, rowsPerBlk), 256, 0, stream>>>(                       \
            IN, Bp + bpOff[LI], tblL[LI], F(wIdx[LI] + 1), F(wIdx[LI] + 2),   \
            OUTB, NOUT, NIN);                                                 \
  } while (0)

  // stage 1
  buildSeq(0);
  CONV(27, 8, 16, 1, 1, f0, 0, bufA, N0, N0);      // conv_in
  CONV(27, 16, 16, 2, 1, bufA, 1, bufB, N0, N0);   // conv1
  // stage 2
  buildSeq(1);
  CONV(27, 16, 32, 1, 2, bufB, 2, bufA, n2, N0);   // conv2a
  buildSeq(2);
  CONV(27, 32, 32, 2, 2, bufA, 3, bufB, n2, n2);   // conv2b
  CONV(27, 32, 32, 2, 2, bufB, 4, bufA, n2, n2);   // conv2c
  // stage 3
  buildSeq(3);
  CONV(27, 32, 64, 1, 2, bufA, 5, bufB, n3, n2);   // conv3a
  buildSeq(4);
  CONV(27, 64, 64, 1, 2, bufB, 6, bufA, n3, n3);   // conv3b
  CONV(27, 64, 64, 1, 2, bufA, 7, bufB, n3, n3);   // conv3c
  // stage 4
  buildSeq(5);
  CONV(27, 64, 64, 1, 1, bufB, 8, bufA, n4, n3);   // conv4a
  buildSeq(6);
  CONV(27, 64, 64, 1, 1, bufA, 9, bufB, n4, n4);   // conv4b
  CONV(27, 64, 64, 1, 1, bufB, 10, bufA, n4, n4);  // conv4c
  // out conv
  buildSeq(7);
  CONV(3, 64, 128, 1, 2, bufA, 11, bufB, no, n4);  // conv_out

  segmax2<<<cdiv_i(no, 128), 256, 0, stream>>>(bufB, I(22), no, (float*)d_out);
#undef CONV
}

// Round 4
// 483.287 us; speedup vs baseline: 4.2030x; 1.2020x over previous
//
#include <hip/hip_runtime.h>
#include <cstddef>
#include <cstdint>

typedef _Float16 half8 __attribute__((ext_vector_type(8)));
typedef float floatx4 __attribute__((ext_vector_type(4)));

static inline int cdiv_i(int a, int b) { return (a + b - 1) / b; }

// ---- input features (f16, padded Ci=8): f[i][c] = sum_p vox[i][p][c]/max(np,1)
__global__ void feat_kernel(const float* __restrict__ vox,
                            const int* __restrict__ vnp,
                            _Float16* __restrict__ f, int N0) {
  int t = blockIdx.x * blockDim.x + threadIdx.x;
  if (t >= (N0 + 1) * 8) return;
  int i = t >> 3, c = t & 7;
  float v = 0.f;
  if (i < N0 && c < 4) {
    const float* p = vox + (size_t)i * 20 + c;
    v = (p[0] + p[4] + p[8] + p[12] + p[16]) / fmaxf((float)vnp[i], 1.f);
  }
  f[t] = (_Float16)v;
}

// ---- fused rulebook inversion, TRANSPOSED tables: tbl[k*nout + o] = in
// (consecutive e within one k have sorted o -> near-contiguous stores)
struct RB { const int* rin; const int* rout; int K, R, nout, start, end, off; };
struct RBs { RB d[8]; };
__global__ void rb_fill_all(RBs P, int* __restrict__ tbl, int total) {
  int idx = blockIdx.x * blockDim.x + threadIdx.x;
  if (idx >= total) return;
#pragma unroll
  for (int l = 0; l < 8; ++l) {
    if (idx >= P.d[l].start && idx < P.d[l].end) {
      const RB rb = P.d[l];
      int e = idx - rb.start;
      int o = rb.rout[e];
      if ((unsigned)o < (unsigned)rb.nout) {
        int k = e / rb.R;
        tbl[rb.off + (size_t)k * rb.nout + o] = rb.rin[e];
      }
    }
  }
}

// single-rulebook fill (fallback when ws is tight), transposed
__global__ void tbl_fill_kernel(const int* __restrict__ rin,
                                const int* __restrict__ rout,
                                int* __restrict__ tbl, int K, int R, int nout) {
  int e = blockIdx.x * blockDim.x + threadIdx.x;
  if (e >= K * R) return;
  int o = rout[e];
  if ((unsigned)o >= (unsigned)nout) return;
  int k = e / R;
  tbl[(size_t)k * nout + o] = rin[e];
}

// ---- fused weight pack: fp32 W[k][ci][co] -> f16 B-fragment panels.
struct WP { const float* W; int K, Ci, CiPad, Co, start, end, off; };
struct WPs { WP d[12]; };
__global__ void wpack_all(WPs P, _Float16* __restrict__ Bp, int total) {
  int idx = blockIdx.x * blockDim.x + threadIdx.x;
  if (idx >= total) return;
#pragma unroll
  for (int l = 0; l < 12; ++l) {
    if (idx >= P.d[l].start && idx < P.d[l].end) {
      const WP w = P.d[l];
      int e = idx - w.start;
      int j = e & 7;
      int lane = (e >> 3) & 63;
      int rest = e >> 9;
      int NT = w.Co >> 4;
      int t = rest % NT, ch = rest / NT;
      int kk = ch * 32 + ((lane >> 4) << 3) + j;
      int k = kk / w.CiPad, ci = kk % w.CiPad;
      int n = t * 16 + (lane & 15);
      float v = (k < w.K && ci < w.Ci)
                    ? w.W[((size_t)k * w.Ci + ci) * w.Co + n]
                    : 0.f;
      Bp[w.off + e] = (_Float16)v;
    }
  }
}

// ---- gather-GEMM conv via MFMA 16x16x32 f16, fp32 accum, fused BN+ReLU.
// Transposed table; ALL row-indices preloaded to VGPRs; A gathers software-
// pipelined 1 deep through a fully-unrolled chunk loop.
template <int K, int CiPad, int Co, int T, int NTW>
__global__ __launch_bounds__(256) void conv_mfma(
    const _Float16* __restrict__ feat, const _Float16* __restrict__ Bp,
    const int* __restrict__ tbl, const float* __restrict__ sc,
    const float* __restrict__ bi, _Float16* __restrict__ out,
    int nout, int nin) {
  constexpr int NT = Co / 16;
  constexpr int colG = NT / NTW;       // waves along columns
  constexpr int rowG = 4 / colG;       // waves along rows
  static_assert(4 % colG == 0, "colG must divide 4");
  constexpr int NCH = (K * CiPad + 31) / 32;
  constexpr int L2C = (CiPad == 8) ? 3 : (CiPad == 16) ? 4 : (CiPad == 32) ? 5 : 6;
  if (blockIdx.x == 0 && threadIdx.x < Co)
    out[(size_t)nout * Co + threadIdx.x] = (_Float16)0.f;  // zero pad row
  const int wave = threadIdx.x >> 6, lane = threadIdx.x & 63;
  const int rowg = wave / colG, colg = wave % colG;
  const int m = lane & 15;
  const int lb = (lane >> 4) * 8;
  const int i0 = (blockIdx.x * rowG + rowg) * (16 * T);
  if (i0 >= nout) return;

  int rows[T];
#pragma unroll
  for (int t = 0; t < T; ++t) rows[t] = i0 + t * 16 + m;

  // ---- preload all gather indices (coalesced: 16 consecutive ints per quad)
  int idx[T][NCH];
#pragma unroll
  for (int ch = 0; ch < NCH; ++ch) {
    int ko = (ch * 32 + lb) >> L2C;
#pragma unroll
    for (int t = 0; t < T; ++t) {
      int jj = (rows[t] < nout && ko < K) ? tbl[(size_t)ko * nout + rows[t]] : -1;
      idx[t][ch] = (jj < 0) ? nin : jj;
    }
  }

  floatx4 acc[T][NTW];
#pragma unroll
  for (int t = 0; t < T; ++t)
#pragma unroll
    for (int n = 0; n < NTW; ++n) {
      floatx4 z = {0.f, 0.f, 0.f, 0.f};
      acc[t][n] = z;
    }

  half8 aN[T];
#pragma unroll
  for (int t = 0; t < T; ++t)
    aN[t] = *(const half8*)(feat + (size_t)idx[t][0] * CiPad + (lb & (CiPad - 1)));

#pragma unroll
  for (int ch = 0; ch < NCH; ++ch) {
    half8 aC[T];
#pragma unroll
    for (int t = 0; t < T; ++t) aC[t] = aN[t];
    if (ch + 1 < NCH) {
      int ci0 = ((ch + 1) * 32 + lb) & (CiPad - 1);
#pragma unroll
      for (int t = 0; t < T; ++t)
        aN[t] = *(const half8*)(feat + (size_t)idx[t][ch + 1] * CiPad + ci0);
    }
    const _Float16* bp = Bp + ((size_t)ch * NT * 64 + lane) * 8;
#pragma unroll
    for (int n = 0; n < NTW; ++n) {
      half8 b = *(const half8*)(bp + (colg * NTW + n) * 512);
#pragma unroll
      for (int t = 0; t < T; ++t)
        acc[t][n] =
            __builtin_amdgcn_mfma_f32_16x16x32_f16(aC[t], b, acc[t][n], 0, 0, 0);
    }
  }

  // epilogue: C/D layout col=lane&15, row=(lane>>4)*4+reg
#pragma unroll
  for (int n = 0; n < NTW; ++n) {
    int col = (colg * NTW + n) * 16 + m;
    float s_ = sc[col], b_ = bi[col];
#pragma unroll
    for (int t = 0; t < T; ++t) {
#pragma unroll
      for (int r = 0; r < 4; ++r) {
        int orow = i0 + t * 16 + (lane >> 4) * 4 + r;
        if (orow < nout) {
          float v = fmaxf(fmaf(acc[t][n][r], s_, b_), 0.f);
          out[(size_t)orow * Co + col] = (_Float16)v;
        }
      }
    }
  }
}

// ---- two-stage segment max; batch_out nondecreasing; one atomic per run.
__global__ __launch_bounds__(256) void segmax2(const _Float16* __restrict__ x,
                                               const int* __restrict__ batch,
                                               int n, float* __restrict__ out) {
  const int RPB = 128;
  int c = threadIdx.x & 127, g = threadIdx.x >> 7;
  int r0 = blockIdx.x * RPB + g;
  int rend = min(n, blockIdx.x * RPB + RPB);
  float mx = 0.f;
  int cb = -1;
  for (int r = r0; r < rend; r += 2) {
    int b = batch[r];
    if (b != cb) {
      if (cb >= 0)
        atomicMax((int*)out + ((size_t)cb << 7) + c, __float_as_int(mx));
      cb = b;
      mx = 0.f;
    }
    mx = fmaxf(mx, (float)x[(size_t)r * 128 + c]);
  }
  if (cb >= 0)
    atomicMax((int*)out + ((size_t)cb << 7) + c, __float_as_int(mx));
}

extern "C" void kernel_launch(void* const* d_in, const int* in_sizes, int n_in,
                              void* d_out, int out_size, void* d_ws, size_t ws_size,
                              hipStream_t stream) {
  auto I = [&](int idx) { return (const int*)d_in[idx]; };
  auto F = [&](int idx) { return (const float*)d_in[idx]; };

  const int N0  = in_sizes[1];
  const int R1  = in_sizes[3] / 27;
  const int R2s = in_sizes[5] / 27;
  const int n2  = in_sizes[7];
  const int R2  = in_sizes[8] / 27;
  const int R3s = in_sizes[10] / 27;
  const int n3  = in_sizes[12];
  const int R3  = in_sizes[13] / 27;
  const int R4s = in_sizes[15] / 27;
  const int n4  = in_sizes[17];
  const int R4  = in_sizes[18] / 27;
  const int Ro  = in_sizes[20] / 3;
  const int no  = in_sizes[22];

  // ---- weight pack descriptors (12 layers)
  const int wIdx[12] = {23, 26, 29, 32, 35, 38, 41, 44, 47, 50, 53, 56};
  const int Ks[12]   = {27, 27, 27, 27, 27, 27, 27, 27, 27, 27, 27, 3};
  const int Cis[12]  = {4, 16, 16, 32, 32, 32, 64, 64, 64, 64, 64, 64};
  const int Cos[12]  = {16, 16, 32, 32, 32, 64, 64, 64, 64, 64, 64, 128};
  WPs P;
  int wtot = 0;
  int bpOff[12];
  for (int l = 0; l < 12; ++l) {
    int cip = Cis[l] < 8 ? 8 : Cis[l];
    int nch = (Ks[l] * cip + 31) / 32;
    int nt = Cos[l] / 16;
    int sz = nch * nt * 512;
    P.d[l].W = F(wIdx[l]);
    P.d[l].K = Ks[l];  P.d[l].Ci = Cis[l];  P.d[l].CiPad = cip;  P.d[l].Co = Cos[l];
    P.d[l].start = wtot;  P.d[l].end = wtot + sz;  P.d[l].off = wtot;
    bpOff[l] = wtot;
    wtot += sz;
  }

  // ---- rulebook descriptors (8 tables)
  RBs RP;
  const int rbRin[8]  = {3, 5, 8, 10, 13, 15, 18, 20};
  const int rbRs[8]   = {R1, R2s, R2, R3s, R3, R4s, R4, Ro};
  const int rbKs[8]   = {27, 27, 27, 27, 27, 27, 27, 3};
  const int rbNout[8] = {N0, n2, n2, n3, n3, n4, n4, no};
  size_t tblInts[8];
  size_t tblOff[8];
  size_t totTbl = 0;
  int totFill = 0;
  for (int l = 0; l < 8; ++l) {
    tblInts[l] = (size_t)rbNout[l] * rbKs[l];
    tblOff[l] = totTbl;
    totTbl += tblInts[l];
    RP.d[l].rin = I(rbRin[l]);
    RP.d[l].rout = I(rbRin[l] + 1);
    RP.d[l].K = rbKs[l];  RP.d[l].R = rbRs[l];  RP.d[l].nout = rbNout[l];
    RP.d[l].start = totFill;
    totFill += rbKs[l] * rbRs[l];
    RP.d[l].end = totFill;
    RP.d[l].off = (int)tblOff[l];
  }

  // ---- workspace layout (halves)
  size_t S = (size_t)(N0 + 1) * 16;
  auto smax = [&](size_t v) { if (v > S) S = v; };
  smax((size_t)(n2 + 1) * 32);
  smax((size_t)(n3 + 1) * 64);
  smax((size_t)(n4 + 1) * 64);
  smax((size_t)(no + 1) * 128);
  S = (S + 7) & ~(size_t)7;

  _Float16* h = (_Float16*)d_ws;
  size_t off = 0;
  _Float16* f0 = h + off;   off += (size_t)(N0 + 1) * 8;
  _Float16* bufA = h + off; off += S;
  _Float16* bufB = h + off; off += S;
  _Float16* Bp = h + off;   off += (size_t)((wtot + 7) & ~7);
  int* tblBase = (int*)(h + off);
  size_t usedBytes = off * 2;
  bool prebuilt = (usedBytes + totTbl * 4 <= ws_size);

  // ---- prep
  feat_kernel<<<cdiv_i((N0 + 1) * 8, 256), 256, 0, stream>>>(F(0), I(1), f0, N0);
  wpack_all<<<cdiv_i(wtot, 256), 256, 0, stream>>>(P, Bp, wtot);
  hipMemsetAsync(d_out, 0, (size_t)out_size * 4, stream);

  const int l2rb[12] = {0, 0, 1, 2, 2, 3, 4, 4, 5, 6, 6, 7};
  const int* tblL[12];
  if (prebuilt) {
    hipMemsetAsync(tblBase, 0xFF, totTbl * 4, stream);
    rb_fill_all<<<cdiv_i(totFill, 256), 256, 0, stream>>>(RP, tblBase, totFill);
    for (int l = 0; l < 12; ++l) tblL[l] = tblBase + tblOff[l2rb[l]];
  } else {
    for (int l = 0; l < 12; ++l) tblL[l] = tblBase;
  }
  auto buildSeq = [&](int rb) {
    if (prebuilt) return;
    hipMemsetAsync(tblBase, 0xFF, tblInts[rb] * 4, stream);
    tbl_fill_kernel<<<cdiv_i(rbKs[rb] * rbRs[rb], 256), 256, 0, stream>>>(
        I(rbRin[rb]), I(rbRin[rb] + 1), tblBase, rbKs[rb], rbRs[rb], rbNout[rb]);
  };

#define CONV(Kk, CIP, CO, Tt, NTWv, IN, LI, OUTB, NOUT, NIN)                  \
  do {                                                                        \
    constexpr int rowsPerBlk = (4 / ((CO / 16) / NTWv)) * 16 * Tt;            \
    conv_mfma<Kk, CIP, CO, Tt, NTWv>                                          \
        <<<cdiv_i(NOUT, rowsPerBlk), 256, 0, stream>>>(                       \
            IN, Bp + bpOff[LI], tblL[LI], F(wIdx[LI] + 1), F(wIdx[LI] + 2),   \
            OUTB, NOUT, NIN);                                                 \
  } while (0)

  // stage 1
  buildSeq(0);
  CONV(27, 8, 16, 2, 1, f0, 0, bufA, N0, N0);      // conv_in
  CONV(27, 16, 16, 2, 1, bufA, 1, bufB, N0, N0);   // conv1
  // stage 2
  buildSeq(1);
  CONV(27, 16, 32, 2, 2, bufB, 2, bufA, n2, N0);   // conv2a
  buildSeq(2);
  CONV(27, 32, 32, 2, 2, bufA, 3, bufB, n2, n2);   // conv2b
  CONV(27, 32, 32, 2, 2, bufB, 4, bufA, n2, n2);   // conv2c
  // stage 3
  buildSeq(3);
  CONV(27, 32, 64, 2, 2, bufA, 5, bufB, n3, n2);   // conv3a
  buildSeq(4);
  CONV(27, 64, 64, 1, 2, bufB, 6, bufA, n3, n3);   // conv3b
  CONV(27, 64, 64, 1, 2, bufA, 7, bufB, n3, n3);   // conv3c
  // stage 4
  buildSeq(5);
  CONV(27, 64, 64, 1, 2, bufB, 8, bufA, n4, n3);   // conv4a
  buildSeq(6);
  CONV(27, 64, 64, 1, 2, bufA, 9, bufB, n4, n4);   // conv4b
  CONV(27, 64, 64, 1, 2, bufB, 10, bufA, n4, n4);  // conv4c
  // out conv
  buildSeq(7);
  CONV(3, 64, 128, 1, 4, bufA, 11, bufB, no, n4);  // conv_out

  segmax2<<<cdiv_i(no, 128), 256, 0, stream>>>(bufB, I(22), no, (float*)d_out);
#undef CONV
}

// Round 5
// 480.434 us; speedup vs baseline: 4.2280x; 1.0059x over previous
//
#include <hip/hip_runtime.h>
#include <cstddef>
#include <cstdint>

typedef _Float16 half8 __attribute__((ext_vector_type(8)));
typedef float floatx4 __attribute__((ext_vector_type(4)));

static inline int cdiv_i(int a, int b) { return (a + b - 1) / b; }

// ---- input features (f16, padded Ci=8): f[i][c] = sum_p vox[i][p][c]/max(np,1)
__global__ void feat_kernel(const float* __restrict__ vox,
                            const int* __restrict__ vnp,
                            _Float16* __restrict__ f, int N0) {
  int t = blockIdx.x * blockDim.x + threadIdx.x;
  if (t >= (N0 + 1) * 8) return;
  int i = t >> 3, c = t & 7;
  float v = 0.f;
  if (i < N0 && c < 4) {
    const float* p = vox + (size_t)i * 20 + c;
    v = (p[0] + p[4] + p[8] + p[12] + p[16]) / fmaxf((float)vnp[i], 1.f);
  }
  f[t] = (_Float16)v;
}

// ---- fused rulebook inversion, TRANSPOSED tables: tbl[k*nout + o] = in
struct RB { const int* rin; const int* rout; int K, R, nout, start, end, off; };
struct RBs { RB d[8]; };
__global__ void rb_fill_all(RBs P, int* __restrict__ tbl, int total) {
  int idx = blockIdx.x * blockDim.x + threadIdx.x;
  if (idx >= total) return;
#pragma unroll
  for (int l = 0; l < 8; ++l) {
    if (idx >= P.d[l].start && idx < P.d[l].end) {
      const RB rb = P.d[l];
      int e = idx - rb.start;
      int o = rb.rout[e];
      if ((unsigned)o < (unsigned)rb.nout) {
        int k = e / rb.R;
        tbl[rb.off + (size_t)k * rb.nout + o] = rb.rin[e];
      }
    }
  }
}

// single-rulebook fill (fallback when ws is tight), transposed
__global__ void tbl_fill_kernel(const int* __restrict__ rin,
                                const int* __restrict__ rout,
                                int* __restrict__ tbl, int K, int R, int nout) {
  int e = blockIdx.x * blockDim.x + threadIdx.x;
  if (e >= K * R) return;
  int o = rout[e];
  if ((unsigned)o >= (unsigned)nout) return;
  int k = e / R;
  tbl[(size_t)k * nout + o] = rin[e];
}

// ---- fused weight pack: fp32 W[k][ci][co] -> f16 B-fragment panels.
struct WP { const float* W; int K, Ci, CiPad, Co, start, end, off; };
struct WPs { WP d[12]; };
__global__ void wpack_all(WPs P, _Float16* __restrict__ Bp, int total) {
  int idx = blockIdx.x * blockDim.x + threadIdx.x;
  if (idx >= total) return;
#pragma unroll
  for (int l = 0; l < 12; ++l) {
    if (idx >= P.d[l].start && idx < P.d[l].end) {
      const WP w = P.d[l];
      int e = idx - w.start;
      int j = e & 7;
      int lane = (e >> 3) & 63;
      int rest = e >> 9;
      int NT = w.Co >> 4;
      int t = rest % NT, ch = rest / NT;
      int kk = ch * 32 + ((lane >> 4) << 3) + j;
      int k = kk / w.CiPad, ci = kk % w.CiPad;
      int n = t * 16 + (lane & 15);
      float v = (k < w.K && ci < w.Ci)
                    ? w.W[((size_t)k * w.Ci + ci) * w.Co + n]
                    : 0.f;
      Bp[w.off + e] = (_Float16)v;
    }
  }
}

// ---- gather-GEMM conv via MFMA 16x16x32 f16, fp32 accum, fused BN+ReLU.
// Transposed table; K distinct row-indices deduped into VGPRs (CiPad>=32);
// explicit DEPTH-deep gather pipeline to keep >=4 gathers in flight.
template <int K, int CiPad, int Co, int T, int NTW>
__global__ __launch_bounds__(256) void conv_mfma(
    const _Float16* __restrict__ feat, const _Float16* __restrict__ Bp,
    const int* __restrict__ tbl, const float* __restrict__ sc,
    const float* __restrict__ bi, _Float16* __restrict__ out,
    int nout, int nin) {
  constexpr int NT = Co / 16;
  constexpr int colG = NT / NTW;       // waves along columns
  constexpr int rowG = 4 / colG;       // waves along rows
  static_assert(4 % colG == 0, "colG must divide 4");
  constexpr int NCH = (K * CiPad + 31) / 32;
  constexpr int DIV = (CiPad >= 32) ? (CiPad / 32) : 1;
  constexpr int NIDX = (CiPad >= 32) ? K : NCH;   // dedup for wide rows
  constexpr int L2C = (CiPad == 8) ? 3 : (CiPad == 16) ? 4 : (CiPad == 32) ? 5 : 6;
  constexpr int DEPTH = (NCH < 4) ? NCH : 4;
  if (blockIdx.x == 0 && threadIdx.x < Co)
    out[(size_t)nout * Co + threadIdx.x] = (_Float16)0.f;  // zero pad row
  const int wave = threadIdx.x >> 6, lane = threadIdx.x & 63;
  const int rowg = wave / colG, colg = wave % colG;
  const int m = lane & 15;
  const int lb = (lane >> 4) * 8;
  const int i0 = (blockIdx.x * rowG + rowg) * (16 * T);
  if (i0 >= nout) return;

  int rows[T];
#pragma unroll
  for (int t = 0; t < T; ++t) rows[t] = i0 + t * 16 + m;

  // ---- preload distinct gather indices (coalesced tbl reads)
  int idx[T][NIDX];
#pragma unroll
  for (int q = 0; q < NIDX; ++q) {
    int ko = (CiPad >= 32) ? q : ((q * 32 + lb) >> L2C);
#pragma unroll
    for (int t = 0; t < T; ++t) {
      int jj = (rows[t] < nout && ko < K) ? tbl[(size_t)ko * nout + rows[t]] : -1;
      idx[t][q] = (jj < 0) ? nin : jj;
    }
  }

  floatx4 acc[T][NTW];
#pragma unroll
  for (int t = 0; t < T; ++t)
#pragma unroll
    for (int n = 0; n < NTW; ++n) {
      floatx4 z = {0.f, 0.f, 0.f, 0.f};
      acc[t][n] = z;
    }

  // ---- DEPTH-deep software pipeline of A gathers
  half8 pipe[DEPTH][T];
#pragma unroll
  for (int d = 0; d < DEPTH; ++d) {
    int kq = d / DIV;
    int ci0 = (d * 32 + lb) & (CiPad - 1);
#pragma unroll
    for (int t = 0; t < T; ++t)
      pipe[d][t] = *(const half8*)(feat + (size_t)idx[t][kq] * CiPad + ci0);
  }

#pragma unroll
  for (int ch = 0; ch < NCH; ++ch) {
    half8 aC[T];
#pragma unroll
    for (int t = 0; t < T; ++t) aC[t] = pipe[ch % DEPTH][t];
    if (ch + DEPTH < NCH) {
      int nx = ch + DEPTH;
      int kq = nx / DIV;
      int ci0 = (nx * 32 + lb) & (CiPad - 1);
#pragma unroll
      for (int t = 0; t < T; ++t)
        pipe[ch % DEPTH][t] =
            *(const half8*)(feat + (size_t)idx[t][kq] * CiPad + ci0);
    }
    const _Float16* bp = Bp + ((size_t)ch * NT * 64 + lane) * 8;
#pragma unroll
    for (int n = 0; n < NTW; ++n) {
      half8 b = *(const half8*)(bp + (colg * NTW + n) * 512);
#pragma unroll
      for (int t = 0; t < T; ++t)
        acc[t][n] =
            __builtin_amdgcn_mfma_f32_16x16x32_f16(aC[t], b, acc[t][n], 0, 0, 0);
    }
  }

  // epilogue: C/D layout col=lane&15, row=(lane>>4)*4+reg
#pragma unroll
  for (int n = 0; n < NTW; ++n) {
    int col = (colg * NTW + n) * 16 + m;
    float s_ = sc[col], b_ = bi[col];
#pragma unroll
    for (int t = 0; t < T; ++t) {
#pragma unroll
      for (int r = 0; r < 4; ++r) {
        int orow = i0 + t * 16 + (lane >> 4) * 4 + r;
        if (orow < nout) {
          float v = fmaxf(fmaf(acc[t][n][r], s_, b_), 0.f);
          out[(size_t)orow * Co + col] = (_Float16)v;
        }
      }
    }
  }
}

// ---- two-stage segment max; batch_out nondecreasing; one atomic per run.
__global__ __launch_bounds__(256) void segmax2(const _Float16* __restrict__ x,
                                               const int* __restrict__ batch,
                                               int n, float* __restrict__ out) {
  const int RPB = 128;
  int c = threadIdx.x & 127, g = threadIdx.x >> 7;
  int r0 = blockIdx.x * RPB + g;
  int rend = min(n, blockIdx.x * RPB + RPB);
  float mx = 0.f;
  int cb = -1;
  for (int r = r0; r < rend; r += 2) {
    int b = batch[r];
    if (b != cb) {
      if (cb >= 0)
        atomicMax((int*)out + ((size_t)cb << 7) + c, __float_as_int(mx));
      cb = b;
      mx = 0.f;
    }
    mx = fmaxf(mx, (float)x[(size_t)r * 128 + c]);
  }
  if (cb >= 0)
    atomicMax((int*)out + ((size_t)cb << 7) + c, __float_as_int(mx));
}

extern "C" void kernel_launch(void* const* d_in, const int* in_sizes, int n_in,
                              void* d_out, int out_size, void* d_ws, size_t ws_size,
                              hipStream_t stream) {
  auto I = [&](int idx) { return (const int*)d_in[idx]; };
  auto F = [&](int idx) { return (const float*)d_in[idx]; };

  const int N0  = in_sizes[1];
  const int R1  = in_sizes[3] / 27;
  const int R2s = in_sizes[5] / 27;
  const int n2  = in_sizes[7];
  const int R2  = in_sizes[8] / 27;
  const int R3s = in_sizes[10] / 27;
  const int n3  = in_sizes[12];
  const int R3  = in_sizes[13] / 27;
  const int R4s = in_sizes[15] / 27;
  const int n4  = in_sizes[17];
  const int R4  = in_sizes[18] / 27;
  const int Ro  = in_sizes[20] / 3;
  const int no  = in_sizes[22];

  // ---- weight pack descriptors (12 layers)
  const int wIdx[12] = {23, 26, 29, 32, 35, 38, 41, 44, 47, 50, 53, 56};
  const int Ks[12]   = {27, 27, 27, 27, 27, 27, 27, 27, 27, 27, 27, 3};
  const int Cis[12]  = {4, 16, 16, 32, 32, 32, 64, 64, 64, 64, 64, 64};
  const int Cos[12]  = {16, 16, 32, 32, 32, 64, 64, 64, 64, 64, 64, 128};
  WPs P;
  int wtot = 0;
  int bpOff[12];
  for (int l = 0; l < 12; ++l) {
    int cip = Cis[l] < 8 ? 8 : Cis[l];
    int nch = (Ks[l] * cip + 31) / 32;
    int nt = Cos[l] / 16;
    int sz = nch * nt * 512;
    P.d[l].W = F(wIdx[l]);
    P.d[l].K = Ks[l];  P.d[l].Ci = Cis[l];  P.d[l].CiPad = cip;  P.d[l].Co = Cos[l];
    P.d[l].start = wtot;  P.d[l].end = wtot + sz;  P.d[l].off = wtot;
    bpOff[l] = wtot;
    wtot += sz;
  }

  // ---- rulebook descriptors (8 tables)
  RBs RP;
  const int rbRin[8]  = {3, 5, 8, 10, 13, 15, 18, 20};
  const int rbRs[8]   = {R1, R2s, R2, R3s, R3, R4s, R4, Ro};
  const int rbKs[8]   = {27, 27, 27, 27, 27, 27, 27, 3};
  const int rbNout[8] = {N0, n2, n2, n3, n3, n4, n4, no};
  size_t tblInts[8];
  size_t tblOff[8];
  size_t totTbl = 0;
  int totFill = 0;
  for (int l = 0; l < 8; ++l) {
    tblInts[l] = (size_t)rbNout[l] * rbKs[l];
    tblOff[l] = totTbl;
    totTbl += tblInts[l];
    RP.d[l].rin = I(rbRin[l]);
    RP.d[l].rout = I(rbRin[l] + 1);
    RP.d[l].K = rbKs[l];  RP.d[l].R = rbRs[l];  RP.d[l].nout = rbNout[l];
    RP.d[l].start = totFill;
    totFill += rbKs[l] * rbRs[l];
    RP.d[l].end = totFill;
    RP.d[l].off = (int)tblOff[l];
  }

  // ---- workspace layout (halves)
  size_t S = (size_t)(N0 + 1) * 16;
  auto smax = [&](size_t v) { if (v > S) S = v; };
  smax((size_t)(n2 + 1) * 32);
  smax((size_t)(n3 + 1) * 64);
  smax((size_t)(n4 + 1) * 64);
  smax((size_t)(no + 1) * 128);
  S = (S + 7) & ~(size_t)7;

  _Float16* h = (_Float16*)d_ws;
  size_t off = 0;
  _Float16* f0 = h + off;   off += (size_t)(N0 + 1) * 8;
  _Float16* bufA = h + off; off += S;
  _Float16* bufB = h + off; off += S;
  _Float16* Bp = h + off;   off += (size_t)((wtot + 7) & ~7);
  int* tblBase = (int*)(h + off);
  size_t usedBytes = off * 2;
  bool prebuilt = (usedBytes + totTbl * 4 <= ws_size);

  // ---- prep
  feat_kernel<<<cdiv_i((N0 + 1) * 8, 256), 256, 0, stream>>>(F(0), I(1), f0, N0);
  wpack_all<<<cdiv_i(wtot, 256), 256, 0, stream>>>(P, Bp, wtot);
  hipMemsetAsync(d_out, 0, (size_t)out_size * 4, stream);

  const int l2rb[12] = {0, 0, 1, 2, 2, 3, 4, 4, 5, 6, 6, 7};
  const int* tblL[12];
  if (prebuilt) {
    hipMemsetAsync(tblBase, 0xFF, totTbl * 4, stream);
    rb_fill_all<<<cdiv_i(totFill, 256), 256, 0, stream>>>(RP, tblBase, totFill);
    for (int l = 0; l < 12; ++l) tblL[l] = tblBase + tblOff[l2rb[l]];
  } else {
    for (int l = 0; l < 12; ++l) tblL[l] = tblBase;
  }
  auto buildSeq = [&](int rb) {
    if (prebuilt) return;
    hipMemsetAsync(tblBase, 0xFF, tblInts[rb] * 4, stream);
    tbl_fill_kernel<<<cdiv_i(rbKs[rb] * rbRs[rb], 256), 256, 0, stream>>>(
        I(rbRin[rb]), I(rbRin[rb] + 1), tblBase, rbKs[rb], rbRs[rb], rbNout[rb]);
  };

#define CONV(Kk, CIP, CO, Tt, NTWv, IN, LI, OUTB, NOUT, NIN)                  \
  do {                                                                        \
    constexpr int rowsPerBlk = (4 / ((CO / 16) / NTWv)) * 16 * Tt;            \
    conv_mfma<Kk, CIP, CO, Tt, NTWv>                                          \
        <<<cdiv_i(NOUT, rowsPerBlk), 256, 0, stream>>>(                       \
            IN, Bp + bpOff[LI], tblL[LI], F(wIdx[LI] + 1), F(wIdx[LI] + 2),   \
            OUTB, NOUT, NIN);                                                 \
  } while (0)

  // stage 1
  buildSeq(0);
  CONV(27, 8, 16, 1, 1, f0, 0, bufA, N0, N0);      // conv_in
  CONV(27, 16, 16, 1, 1, bufA, 1, bufB, N0, N0);   // conv1
  // stage 2
  buildSeq(1);
  CONV(27, 16, 32, 1, 2, bufB, 2, bufA, n2, N0);   // conv2a
  buildSeq(2);
  CONV(27, 32, 32, 1, 2, bufA, 3, bufB, n2, n2);   // conv2b
  CONV(27, 32, 32, 1, 2, bufB, 4, bufA, n2, n2);   // conv2c
  // stage 3
  buildSeq(3);
  CONV(27, 32, 64, 1, 2, bufA, 5, bufB, n3, n2);   // conv3a
  buildSeq(4);
  CONV(27, 64, 64, 1, 2, bufB, 6, bufA, n3, n3);   // conv3b
  CONV(27, 64, 64, 1, 2, bufA, 7, bufB, n3, n3);   // conv3c
  // stage 4
  buildSeq(5);
  CONV(27, 64, 64, 1, 2, bufB, 8, bufA, n4, n3);   // conv4a
  buildSeq(6);
  CONV(27, 64, 64, 1, 2, bufA, 9, bufB, n4, n4);   // conv4b
  CONV(27, 64, 64, 1, 2, bufB, 10, bufA, n4, n4);  // conv4c
  // out conv
  buildSeq(7);
  CONV(3, 64, 128, 1, 4, bufA, 11, bufB, no, n4);  // conv_out

  segmax2<<<cdiv_i(no, 128), 256, 0, stream>>>(bufB, I(22), no, (float*)d_out);
#undef CONV
}

// Round 6
// 464.008 us; speedup vs baseline: 4.3776x; 1.0354x over previous
//
#include <hip/hip_runtime.h>
#include <cstddef>
#include <cstdint>

typedef _Float16 half8 __attribute__((ext_vector_type(8)));
typedef float floatx4 __attribute__((ext_vector_type(4)));

static inline int cdiv_i(int a, int b) { return (a + b - 1) / b; }

// ---- input features (f16, padded Ci=8): f[i][c] = sum_p vox[i][p][c]/max(np,1)
__global__ void feat_kernel(const float* __restrict__ vox,
                            const int* __restrict__ vnp,
                            _Float16* __restrict__ f, int N0) {
  int t = blockIdx.x * blockDim.x + threadIdx.x;
  if (t >= (N0 + 1) * 8) return;
  int i = t >> 3, c = t & 7;
  float v = 0.f;
  if (i < N0 && c < 4) {
    const float* p = vox + (size_t)i * 20 + c;
    v = (p[0] + p[4] + p[8] + p[12] + p[16]) / fmaxf((float)vnp[i], 1.f);
  }
  f[t] = (_Float16)v;
}

// ---- fused rulebook inversion, TRANSPOSED tables: tbl[k*nout + o] = in
struct RB { const int* rin; const int* rout; int K, R, nout, start, end, off; };
struct RBs { RB d[8]; };
__global__ void rb_fill_all(RBs P, int* __restrict__ tbl, int total) {
  int idx = blockIdx.x * blockDim.x + threadIdx.x;
  if (idx >= total) return;
#pragma unroll
  for (int l = 0; l < 8; ++l) {
    if (idx >= P.d[l].start && idx < P.d[l].end) {
      const RB rb = P.d[l];
      int e = idx - rb.start;
      int o = rb.rout[e];
      if ((unsigned)o < (unsigned)rb.nout) {
        int k = e / rb.R;
        tbl[rb.off + (size_t)k * rb.nout + o] = rb.rin[e];
      }
    }
  }
}

// single-rulebook fill (fallback when ws is tight), transposed
__global__ void tbl_fill_kernel(const int* __restrict__ rin,
                                const int* __restrict__ rout,
                                int* __restrict__ tbl, int K, int R, int nout) {
  int e = blockIdx.x * blockDim.x + threadIdx.x;
  if (e >= K * R) return;
  int o = rout[e];
  if ((unsigned)o >= (unsigned)nout) return;
  int k = e / R;
  tbl[(size_t)k * nout + o] = rin[e];
}

// ---- fused weight pack: fp32 W[k][ci][co] -> f16 B-fragment panels.
struct WP { const float* W; int K, Ci, CiPad, Co, start, end, off; };
struct WPs { WP d[12]; };
__global__ void wpack_all(WPs P, _Float16* __restrict__ Bp, int total) {
  int idx = blockIdx.x * blockDim.x + threadIdx.x;
  if (idx >= total) return;
#pragma unroll
  for (int l = 0; l < 12; ++l) {
    if (idx >= P.d[l].start && idx < P.d[l].end) {
      const WP w = P.d[l];
      int e = idx - w.start;
      int j = e & 7;
      int lane = (e >> 3) & 63;
      int rest = e >> 9;
      int NT = w.Co >> 4;
      int t = rest % NT, ch = rest / NT;
      int kk = ch * 32 + ((lane >> 4) << 3) + j;
      int k = kk / w.CiPad, ci = kk % w.CiPad;
      int n = t * 16 + (lane & 15);
      float v = (k < w.K && ci < w.Ci)
                    ? w.W[((size_t)k * w.Ci + ci) * w.Co + n]
                    : 0.f;
      Bp[w.off + e] = (_Float16)v;
    }
  }
}

// ---- gather-GEMM conv, MFMA 16x16x32 f16, fp32 accum, fused BN+ReLU.
// Waves factor as KS (k-split, LDS-reduced) x CG (column split) x RG (row split).
// Both A-gathers (DA=4) and B-frag loads (DB=2) run in explicit prefetch rings.
template <int K, int CiPad, int Co, int KS, int CG>
__global__ __launch_bounds__(256) void conv_mfma(
    const _Float16* __restrict__ feat, const _Float16* __restrict__ Bp,
    const int* __restrict__ tbl, const float* __restrict__ sc,
    const float* __restrict__ bi, _Float16* __restrict__ out,
    int nout, int nin) {
  constexpr int NT = Co / 16;
  constexpr int NTW = NT / CG;
  constexpr int RG = 4 / (KS * CG);
  static_assert(KS * CG * RG == 4 && RG >= 1 && NT % CG == 0);
  constexpr int DIV = (CiPad >= 32) ? (CiPad / 32) : 1;
  constexpr int NCH = (K * CiPad + 31) / 32;
  constexpr int L2C = (CiPad == 8) ? 3 : 4;  // used only for CiPad<32
  constexpr int CoP = Co + 4;

  __shared__ float red[(KS > 1) ? (KS - 1) * RG * 16 * CoP : 1];

  if (blockIdx.x == 0 && threadIdx.x < Co)
    out[(size_t)nout * Co + threadIdx.x] = (_Float16)0.f;  // zero pad row

  const int wave = threadIdx.x >> 6, lane = threadIdx.x & 63;
  const int ks = wave % KS;
  const int cg = (wave / KS) % CG;
  const int rowg = wave / (KS * CG);
  const int m = lane & 15, lb = (lane >> 4) * 8;
  const int i0 = (blockIdx.x * RG + rowg) * 16;
  if constexpr (KS == 1) {
    if (i0 >= nout) return;   // no barrier in KS==1 path
  }
  const int row = i0 + m;
  const bool rOK = row < nout;

  floatx4 acc[NTW];
#pragma unroll
  for (int n = 0; n < NTW; ++n) {
    floatx4 z = {0.f, 0.f, 0.f, 0.f};
    acc[n] = z;
  }

  if constexpr (CiPad >= 32) {
    constexpr int NKW = (K + KS - 1) / KS;  // local k count (max over waves)
    constexpr int NC = NKW * DIV;           // flattened chunk iterations
    constexpr int DA = NC < 4 ? NC : 4;
    constexpr int DB = NC < 2 ? NC : 2;
    int idx[NKW];
#pragma unroll
    for (int q = 0; q < NKW; ++q) {
      int k = ks + q * KS;
      int jj = (rOK && k < K) ? tbl[(size_t)k * nout + row] : -1;
      idx[q] = (jj < 0) ? nin : jj;
    }
    half8 ap[DA];
    half8 bq[DB][NTW];
#pragma unroll
    for (int d = 0; d < DA; ++d)
      ap[d] = *(const half8*)(feat + (size_t)idx[d / DIV] * CiPad +
                              (d % DIV) * 32 + lb);
#pragma unroll
    for (int d = 0; d < DB; ++d) {
      int k = ks + (d / DIV) * KS;
      int ch = ((k < K) ? k : (K - 1)) * DIV + (d % DIV);
#pragma unroll
      for (int n = 0; n < NTW; ++n)
        bq[d][n] = *(const half8*)(Bp + ((size_t)ch * NT * 64 + lane) * 8 +
                                   (size_t)(cg * NTW + n) * 512);
    }
#pragma unroll
    for (int ii = 0; ii < NC; ++ii) {
      half8 a = ap[ii % DA];
      half8 bt[NTW];
#pragma unroll
      for (int n = 0; n < NTW; ++n) bt[n] = bq[ii % DB][n];
      if (ii + DA < NC) {
        int nx = ii + DA;
        ap[ii % DA] = *(const half8*)(feat + (size_t)idx[nx / DIV] * CiPad +
                                      (nx % DIV) * 32 + lb);
      }
      if (ii + DB < NC) {
        int nx = ii + DB;
        int k = ks + (nx / DIV) * KS;
        int ch = ((k < K) ? k : (K - 1)) * DIV + (nx % DIV);
#pragma unroll
        for (int n = 0; n < NTW; ++n)
          bq[ii % DB][n] = *(const half8*)(Bp + ((size_t)ch * NT * 64 + lane) * 8 +
                                           (size_t)(cg * NTW + n) * 512);
      }
#pragma unroll
      for (int n = 0; n < NTW; ++n)
        acc[n] = __builtin_amdgcn_mfma_f32_16x16x32_f16(a, bt[n], acc[n], 0, 0, 0);
    }
  } else {
    // CiPad < 32 -> KS==1 always (narrow layers, large n)
    constexpr int NC = NCH;
    constexpr int DA = NC < 4 ? NC : 4;
    constexpr int DB = NC < 2 ? NC : 2;
    int idx[NC];
#pragma unroll
    for (int q = 0; q < NC; ++q) {
      int ko = (q * 32 + lb) >> L2C;
      int jj = (rOK && ko < K) ? tbl[(size_t)ko * nout + row] : -1;
      idx[q] = (jj < 0) ? nin : jj;
    }
    half8 ap[DA];
    half8 bq[DB][NTW];
#pragma unroll
    for (int d = 0; d < DA; ++d)
      ap[d] = *(const half8*)(feat + (size_t)idx[d] * CiPad +
                              ((d * 32 + lb) & (CiPad - 1)));
#pragma unroll
    for (int d = 0; d < DB; ++d)
#pragma unroll
      for (int n = 0; n < NTW; ++n)
        bq[d][n] = *(const half8*)(Bp + ((size_t)d * NT * 64 + lane) * 8 +
                                   (size_t)(cg * NTW + n) * 512);
#pragma unroll
    for (int ii = 0; ii < NC; ++ii) {
      half8 a = ap[ii % DA];
      half8 bt[NTW];
#pragma unroll
      for (int n = 0; n < NTW; ++n) bt[n] = bq[ii % DB][n];
      if (ii + DA < NC) {
        int nx = ii + DA;
        ap[ii % DA] = *(const half8*)(feat + (size_t)idx[nx] * CiPad +
                                      ((nx * 32 + lb) & (CiPad - 1)));
      }
      if (ii + DB < NC) {
        int nx = ii + DB;
#pragma unroll
        for (int n = 0; n < NTW; ++n)
          bq[ii % DB][n] = *(const half8*)(Bp + ((size_t)nx * NT * 64 + lane) * 8 +
                                           (size_t)(cg * NTW + n) * 512);
      }
#pragma unroll
      for (int n = 0; n < NTW; ++n)
        acc[n] = __builtin_amdgcn_mfma_f32_16x16x32_f16(a, bt[n], acc[n], 0, 0, 0);
    }
  }

  const int rl = (lane >> 4) * 4;
  if constexpr (KS > 1) {
    if (ks > 0) {
#pragma unroll
      for (int n = 0; n < NTW; ++n) {
        int col = (cg * NTW + n) * 16 + m;
#pragma unroll
        for (int r = 0; r < 4; ++r)
          red[((ks - 1) * RG + rowg) * 16 * CoP + (rl + r) * CoP + col] = acc[n][r];
      }
    }
    __syncthreads();
    if (ks > 0) return;
#pragma unroll
    for (int s = 1; s < KS; ++s)
#pragma unroll
      for (int n = 0; n < NTW; ++n) {
        int col = (cg * NTW + n) * 16 + m;
#pragma unroll
        for (int r = 0; r < 4; ++r)
          acc[n][r] += red[((s - 1) * RG + rowg) * 16 * CoP + (rl + r) * CoP + col];
      }
  }

  // epilogue: C/D layout col=lane&15, row=(lane>>4)*4+reg
#pragma unroll
  for (int n = 0; n < NTW; ++n) {
    int col = (cg * NTW + n) * 16 + m;
    float s_ = sc[col], b_ = bi[col];
#pragma unroll
    for (int r = 0; r < 4; ++r) {
      int orow = i0 + rl + r;
      if (orow < nout)
        out[(size_t)orow * Co + col] = (_Float16)fmaxf(fmaf(acc[n][r], s_, b_), 0.f);
    }
  }
}

// ---- two-stage segment max; batch_out nondecreasing; one atomic per run.
__global__ __launch_bounds__(256) void segmax2(const _Float16* __restrict__ x,
                                               const int* __restrict__ batch,
                                               int n, float* __restrict__ out) {
  const int RPB = 128;
  int c = threadIdx.x & 127, g = threadIdx.x >> 7;
  int r0 = blockIdx.x * RPB + g;
  int rend = min(n, blockIdx.x * RPB + RPB);
  float mx = 0.f;
  int cb = -1;
  for (int r = r0; r < rend; r += 2) {
    int b = batch[r];
    if (b != cb) {
      if (cb >= 0)
        atomicMax((int*)out + ((size_t)cb << 7) + c, __float_as_int(mx));
      cb = b;
      mx = 0.f;
    }
    mx = fmaxf(mx, (float)x[(size_t)r * 128 + c]);
  }
  if (cb >= 0)
    atomicMax((int*)out + ((size_t)cb << 7) + c, __float_as_int(mx));
}

extern "C" void kernel_launch(void* const* d_in, const int* in_sizes, int n_in,
                              void* d_out, int out_size, void* d_ws, size_t ws_size,
                              hipStream_t stream) {
  auto I = [&](int idx) { return (const int*)d_in[idx]; };
  auto F = [&](int idx) { return (const float*)d_in[idx]; };

  const int N0  = in_sizes[1];
  const int R1  = in_sizes[3] / 27;
  const int R2s = in_sizes[5] / 27;
  const int n2  = in_sizes[7];
  const int R2  = in_sizes[8] / 27;
  const int R3s = in_sizes[10] / 27;
  const int n3  = in_sizes[12];
  const int R3  = in_sizes[13] / 27;
  const int R4s = in_sizes[15] / 27;
  const int n4  = in_sizes[17];
  const int R4  = in_sizes[18] / 27;
  const int Ro  = in_sizes[20] / 3;
  const int no  = in_sizes[22];

  // ---- weight pack descriptors (12 layers)
  const int wIdx[12] = {23, 26, 29, 32, 35, 38, 41, 44, 47, 50, 53, 56};
  const int Ks[12]   = {27, 27, 27, 27, 27, 27, 27, 27, 27, 27, 27, 3};
  const int Cis[12]  = {4, 16, 16, 32, 32, 32, 64, 64, 64, 64, 64, 64};
  const int Cos[12]  = {16, 16, 32, 32, 32, 64, 64, 64, 64, 64, 64, 128};
  WPs P;
  int wtot = 0;
  int bpOff[12];
  for (int l = 0; l < 12; ++l) {
    int cip = Cis[l] < 8 ? 8 : Cis[l];
    int nch = (Ks[l] * cip + 31) / 32;
    int nt = Cos[l] / 16;
    int sz = nch * nt * 512;
    P.d[l].W = F(wIdx[l]);
    P.d[l].K = Ks[l];  P.d[l].Ci = Cis[l];  P.d[l].CiPad = cip;  P.d[l].Co = Cos[l];
    P.d[l].start = wtot;  P.d[l].end = wtot + sz;  P.d[l].off = wtot;
    bpOff[l] = wtot;
    wtot += sz;
  }

  // ---- rulebook descriptors (8 tables)
  RBs RP;
  const int rbRin[8]  = {3, 5, 8, 10, 13, 15, 18, 20};
  const int rbRs[8]   = {R1, R2s, R2, R3s, R3, R4s, R4, Ro};
  const int rbKs[8]   = {27, 27, 27, 27, 27, 27, 27, 3};
  const int rbNout[8] = {N0, n2, n2, n3, n3, n4, n4, no};
  size_t tblInts[8];
  size_t tblOff[8];
  size_t totTbl = 0;
  int totFill = 0;
  for (int l = 0; l < 8; ++l) {
    tblInts[l] = (size_t)rbNout[l] * rbKs[l];
    tblOff[l] = totTbl;
    totTbl += tblInts[l];
    RP.d[l].rin = I(rbRin[l]);
    RP.d[l].rout = I(rbRin[l] + 1);
    RP.d[l].K = rbKs[l];  RP.d[l].R = rbRs[l];  RP.d[l].nout = rbNout[l];
    RP.d[l].start = totFill;
    totFill += rbKs[l] * rbRs[l];
    RP.d[l].end = totFill;
    RP.d[l].off = (int)tblOff[l];
  }

  // ---- workspace layout (halves)
  size_t S = (size_t)(N0 + 1) * 16;
  auto smax = [&](size_t v) { if (v > S) S = v; };
  smax((size_t)(n2 + 1) * 32);
  smax((size_t)(n3 + 1) * 64);
  smax((size_t)(n4 + 1) * 64);
  smax((size_t)(no + 1) * 128);
  S = (S + 7) & ~(size_t)7;

  _Float16* h = (_Float16*)d_ws;
  size_t off = 0;
  _Float16* f0 = h + off;   off += (size_t)(N0 + 1) * 8;
  _Float16* bufA = h + off; off += S;
  _Float16* bufB = h + off; off += S;
  _Float16* Bp = h + off;   off += (size_t)((wtot + 7) & ~7);
  int* tblBase = (int*)(h + off);
  size_t usedBytes = off * 2;
  bool prebuilt = (usedBytes + totTbl * 4 <= ws_size);

  // ---- prep
  feat_kernel<<<cdiv_i((N0 + 1) * 8, 256), 256, 0, stream>>>(F(0), I(1), f0, N0);
  wpack_all<<<cdiv_i(wtot, 256), 256, 0, stream>>>(P, Bp, wtot);
  hipMemsetAsync(d_out, 0, (size_t)out_size * 4, stream);

  const int l2rb[12] = {0, 0, 1, 2, 2, 3, 4, 4, 5, 6, 6, 7};
  const int* tblL[12];
  if (prebuilt) {
    hipMemsetAsync(tblBase, 0xFF, totTbl * 4, stream);
    rb_fill_all<<<cdiv_i(totFill, 256), 256, 0, stream>>>(RP, tblBase, totFill);
    for (int l = 0; l < 12; ++l) tblL[l] = tblBase + tblOff[l2rb[l]];
  } else {
    for (int l = 0; l < 12; ++l) tblL[l] = tblBase;
  }
  auto buildSeq = [&](int rb) {
    if (prebuilt) return;
    hipMemsetAsync(tblBase, 0xFF, tblInts[rb] * 4, stream);
    tbl_fill_kernel<<<cdiv_i(rbKs[rb] * rbRs[rb], 256), 256, 0, stream>>>(
        I(rbRin[rb]), I(rbRin[rb] + 1), tblBase, rbKs[rb], rbRs[rb], rbNout[rb]);
  };

#define CONV(Kk, CIP, CO, KSv, CGv, IN, LI, OUTB, NOUT, NIN)                  \
  do {                                                                        \
    constexpr int rowsPerBlk = (4 / (KSv * CGv)) * 16;                        \
    conv_mfma<Kk, CIP, CO, KSv, CGv>                                          \
        <<<cdiv_i(NOUT, rowsPerBlk), 256, 0, stream>>>(                       \
            IN, Bp + bpOff[LI], tblL[LI], F(wIdx[LI] + 1), F(wIdx[LI] + 2),   \
            OUTB, NOUT, NIN);                                                 \
  } while (0)

  // stage 1 (large n, narrow: row-split only)
  buildSeq(0);
  CONV(27, 8, 16, 1, 1, f0, 0, bufA, N0, N0);      // conv_in
  CONV(27, 16, 16, 1, 1, bufA, 1, bufB, N0, N0);   // conv1
  // stage 2
  buildSeq(1);
  CONV(27, 16, 32, 1, 1, bufB, 2, bufA, n2, N0);   // conv2a  NTW=2
  buildSeq(2);
  CONV(27, 32, 32, 1, 1, bufA, 3, bufB, n2, n2);   // conv2b  NTW=2
  CONV(27, 32, 32, 1, 1, bufB, 4, bufA, n2, n2);   // conv2c
  // stage 3 (k-split starts: fewer rows)
  buildSeq(3);
  CONV(27, 32, 64, 2, 1, bufA, 5, bufB, n3, n2);   // conv3a  KS2, NTW=4
  buildSeq(4);
  CONV(27, 64, 64, 2, 1, bufB, 6, bufA, n3, n3);   // conv3b
  CONV(27, 64, 64, 2, 1, bufA, 7, bufB, n3, n3);   // conv3c
  // stage 4 (few rows: KS4)
  buildSeq(5);
  CONV(27, 64, 64, 4, 1, bufB, 8, bufA, n4, n3);   // conv4a
  buildSeq(6);
  CONV(27, 64, 64, 4, 1, bufA, 9, bufB, n4, n4);   // conv4b
  CONV(27, 64, 64, 4, 1, bufB, 10, bufA, n4, n4);  // conv4c
  // out conv (K=3, Co=128)
  buildSeq(7);
  CONV(3, 64, 128, 2, 2, bufA, 11, bufB, no, n4);  // conv_out NTW=4
  segmax2<<<cdiv_i(no, 128), 256, 0, stream>>>(bufB, I(22), no, (float*)d_out);
#undef CONV
}

// Round 7
// 448.246 us; speedup vs baseline: 4.5316x; 1.0352x over previous
//
#include <hip/hip_runtime.h>
#include <cstddef>
#include <cstdint>

typedef _Float16 half8 __attribute__((ext_vector_type(8)));
typedef float floatx4 __attribute__((ext_vector_type(4)));

static inline int cdiv_i(int a, int b) { return (a + b - 1) / b; }

// ---- input features (f16, padded Ci=8)
__global__ void feat_kernel(const float* __restrict__ vox,
                            const int* __restrict__ vnp,
                            _Float16* __restrict__ f, int N0) {
  int t = blockIdx.x * blockDim.x + threadIdx.x;
  if (t >= (N0 + 1) * 8) return;
  int i = t >> 3, c = t & 7;
  float v = 0.f;
  if (i < N0 && c < 4) {
    const float* p = vox + (size_t)i * 20 + c;
    v = (p[0] + p[4] + p[8] + p[12] + p[16]) / fmaxf((float)vnp[i], 1.f);
  }
  f[t] = (_Float16)v;
}

// ---- fused rulebook inversion, TRANSPOSED tables: tbl[k*nout + o] = in
struct RB { const int* rin; const int* rout; int K, R, nout, start, end, off; };
struct RBs { RB d[8]; };
__global__ void rb_fill_all(RBs P, int* __restrict__ tbl, int total) {
  int idx = blockIdx.x * blockDim.x + threadIdx.x;
  if (idx >= total) return;
#pragma unroll
  for (int l = 0; l < 8; ++l) {
    if (idx >= P.d[l].start && idx < P.d[l].end) {
      const RB rb = P.d[l];
      int e = idx - rb.start;
      int o = rb.rout[e];
      if ((unsigned)o < (unsigned)rb.nout) {
        int k = e / rb.R;
        tbl[rb.off + (size_t)k * rb.nout + o] = rb.rin[e];
      }
    }
  }
}

__global__ void tbl_fill_kernel(const int* __restrict__ rin,
                                const int* __restrict__ rout,
                                int* __restrict__ tbl, int K, int R, int nout) {
  int e = blockIdx.x * blockDim.x + threadIdx.x;
  if (e >= K * R) return;
  int o = rout[e];
  if ((unsigned)o >= (unsigned)nout) return;
  int k = e / R;
  tbl[(size_t)k * nout + o] = rin[e];
}

// ---- fused weight pack: fp32 W[k][ci][co] -> f16 B-fragment panels.
struct WP { const float* W; int K, Ci, CiPad, Co, start, end, off; };
struct WPs { WP d[12]; };
__global__ void wpack_all(WPs P, _Float16* __restrict__ Bp, int total) {
  int idx = blockIdx.x * blockDim.x + threadIdx.x;
  if (idx >= total) return;
#pragma unroll
  for (int l = 0; l < 12; ++l) {
    if (idx >= P.d[l].start && idx < P.d[l].end) {
      const WP w = P.d[l];
      int e = idx - w.start;
      int j = e & 7;
      int lane = (e >> 3) & 63;
      int rest = e >> 9;
      int NT = w.Co >> 4;
      int t = rest % NT, ch = rest / NT;
      int kk = ch * 32 + ((lane >> 4) << 3) + j;
      int k = kk / w.CiPad, ci = kk % w.CiPad;
      int n = t * 16 + (lane & 15);
      float v = (k < w.K && ci < w.Ci)
                    ? w.W[((size_t)k * w.Ci + ci) * w.Co + n]
                    : 0.f;
      Bp[w.off + e] = (_Float16)v;
    }
  }
}

// ---- gather-GEMM conv, MFMA 16x16x32 f16, fp32 accum, fused BN+ReLU.
// Block grid = rowTiles * CBLK (column-split across blocks). Within block,
// waves factor KS (k-split, LDS-reduced) x CG (col split) x RG (row split).
// A-gathers ring DA<=8 deep; B-frag loads ring DB<=2 deep. XCD swizzle maps
// contiguous row-tile ranges to one XCD for gather L2 locality.
template <int K, int CiPad, int Co, int KS, int CG, int CBLK>
__global__ __launch_bounds__(256) void conv_mfma(
    const _Float16* __restrict__ feat, const _Float16* __restrict__ Bp,
    const int* __restrict__ tbl, const float* __restrict__ sc,
    const float* __restrict__ bi, _Float16* __restrict__ out,
    int nout, int nin) {
  constexpr int NT = Co / 16;
  constexpr int NTE = NT / CBLK;       // col tiles per block
  constexpr int NTW = NTE / CG;        // col tiles per wave
  constexpr int RG = 4 / (KS * CG);
  static_assert(KS * CG * RG == 4 && RG >= 1 && NT % CBLK == 0 && NTE % CG == 0);
  constexpr int DIV = (CiPad >= 32) ? (CiPad / 32) : 1;
  constexpr int NCH = (K * CiPad + 31) / 32;
  constexpr int L2C = (CiPad == 8) ? 3 : 4;  // only for CiPad<32
  constexpr int CoP = NTE * 16 + 4;

  __shared__ float red[(KS > 1) ? (KS - 1) * RG * 16 * CoP : 1];

  if (blockIdx.x == 0 && threadIdx.x < Co)
    out[(size_t)nout * Co + threadIdx.x] = (_Float16)0.f;  // zero pad row

  // bijective XCD swizzle: XCD (id%8) gets a contiguous block range
  int id = blockIdx.x;
  {
    int nb = gridDim.x, nb8 = (nb >> 3) << 3;
    if (id < nb8) {
      int per = nb >> 3;
      id = (id & 7) * per + (id >> 3);
    }
  }
  const int rt = id / CBLK, cb = id % CBLK;

  const int wave = threadIdx.x >> 6, lane = threadIdx.x & 63;
  const int ks = wave % KS;
  const int cg = (wave / KS) % CG;
  const int rowg = wave / (KS * CG);
  const int m = lane & 15, lb = (lane >> 4) * 8;
  const int i0 = (rt * RG + rowg) * 16;
  if constexpr (KS == 1) {
    if (i0 >= nout) return;   // no barrier in KS==1 path
  }
  const int row = i0 + m;
  const bool rOK = row < nout;
  const int ct0 = cb * NTE + cg * NTW;   // global col-tile base for this wave

  floatx4 acc[NTW];
#pragma unroll
  for (int n = 0; n < NTW; ++n) {
    floatx4 z = {0.f, 0.f, 0.f, 0.f};
    acc[n] = z;
  }

  if constexpr (CiPad >= 32) {
    constexpr int NKW = (K + KS - 1) / KS;
    constexpr int NC = NKW * DIV;
    constexpr int DA = NC < 8 ? NC : 8;
    constexpr int DB = NC < 2 ? NC : 2;
    int idx[NKW];
#pragma unroll
    for (int q = 0; q < NKW; ++q) {
      int k = ks + q * KS;
      int jj = (rOK && k < K) ? tbl[(size_t)k * nout + row] : -1;
      idx[q] = (jj < 0) ? nin : jj;
    }
    half8 ap[DA];
    half8 bq[DB][NTW];
#pragma unroll
    for (int d = 0; d < DA; ++d)
      ap[d] = *(const half8*)(feat + (size_t)idx[d / DIV] * CiPad +
                              (d % DIV) * 32 + lb);
#pragma unroll
    for (int d = 0; d < DB; ++d) {
      int k = ks + (d / DIV) * KS;
      int ch = ((k < K) ? k : (K - 1)) * DIV + (d % DIV);
#pragma unroll
      for (int n = 0; n < NTW; ++n)
        bq[d][n] = *(const half8*)(Bp + ((size_t)ch * NT * 64 + lane) * 8 +
                                   (size_t)(ct0 + n) * 512);
    }
#pragma unroll
    for (int ii = 0; ii < NC; ++ii) {
      half8 a = ap[ii % DA];
      half8 bt[NTW];
#pragma unroll
      for (int n = 0; n < NTW; ++n) bt[n] = bq[ii % DB][n];
      if (ii + DA < NC) {
        int nx = ii + DA;
        ap[ii % DA] = *(const half8*)(feat + (size_t)idx[nx / DIV] * CiPad +
                                      (nx % DIV) * 32 + lb);
      }
      if (ii + DB < NC) {
        int nx = ii + DB;
        int k = ks + (nx / DIV) * KS;
        int ch = ((k < K) ? k : (K - 1)) * DIV + (nx % DIV);
#pragma unroll
        for (int n = 0; n < NTW; ++n)
          bq[ii % DB][n] = *(const half8*)(Bp + ((size_t)ch * NT * 64 + lane) * 8 +
                                           (size_t)(ct0 + n) * 512);
      }
#pragma unroll
      for (int n = 0; n < NTW; ++n)
        acc[n] = __builtin_amdgcn_mfma_f32_16x16x32_f16(a, bt[n], acc[n], 0, 0, 0);
    }
  } else {
    // narrow path: split the NCH chunks round-robin over KS waves
    constexpr int NCW = (NCH + KS - 1) / KS;
    constexpr int DA = NCW < 8 ? NCW : 8;
    constexpr int DB = NCW < 2 ? NCW : 2;
    int idx[NCW];
#pragma unroll
    for (int q = 0; q < NCW; ++q) {
      int ch = ks + q * KS;
      int ko = (ch * 32 + lb) >> L2C;
      int jj = (rOK && ko < K && ch < NCH) ? tbl[(size_t)ko * nout + row] : -1;
      idx[q] = (jj < 0) ? nin : jj;
    }
    half8 ap[DA];
    half8 bq[DB][NTW];
#pragma unroll
    for (int d = 0; d < DA; ++d) {
      int ch = ks + d * KS;
      ap[d] = *(const half8*)(feat + (size_t)idx[d] * CiPad +
                              ((ch * 32 + lb) & (CiPad - 1)));
    }
#pragma unroll
    for (int d = 0; d < DB; ++d) {
      int ch = ks + d * KS;
      if (ch >= NCH) ch = NCH - 1;
#pragma unroll
      for (int n = 0; n < NTW; ++n)
        bq[d][n] = *(const half8*)(Bp + ((size_t)ch * NT * 64 + lane) * 8 +
                                   (size_t)(ct0 + n) * 512);
    }
#pragma unroll
    for (int ii = 0; ii < NCW; ++ii) {
      half8 a = ap[ii % DA];
      half8 bt[NTW];
#pragma unroll
      for (int n = 0; n < NTW; ++n) bt[n] = bq[ii % DB][n];
      if (ii + DA < NCW) {
        int nx = ii + DA;
        int ch = ks + nx * KS;
        ap[ii % DA] = *(const half8*)(feat + (size_t)idx[nx] * CiPad +
                                      ((ch * 32 + lb) & (CiPad - 1)));
      }
      if (ii + DB < NCW) {
        int nx = ii + DB;
        int ch = ks + nx * KS;
        if (ch >= NCH) ch = NCH - 1;
#pragma unroll
        for (int n = 0; n < NTW; ++n)
          bq[ii % DB][n] = *(const half8*)(Bp + ((size_t)ch * NT * 64 + lane) * 8 +
                                           (size_t)(ct0 + n) * 512);
      }
#pragma unroll
      for (int n = 0; n < NTW; ++n)
        acc[n] = __builtin_amdgcn_mfma_f32_16x16x32_f16(a, bt[n], acc[n], 0, 0, 0);
    }
  }

  const int rl = (lane >> 4) * 4;
  if constexpr (KS > 1) {
    if (ks > 0) {
#pragma unroll
      for (int n = 0; n < NTW; ++n) {
        int lcol = (cg * NTW + n) * 16 + m;
#pragma unroll
        for (int r = 0; r < 4; ++r)
          red[((ks - 1) * RG + rowg) * 16 * CoP + (rl + r) * CoP + lcol] = acc[n][r];
      }
    }
    __syncthreads();
    if (ks > 0) return;
#pragma unroll
    for (int s = 1; s < KS; ++s)
#pragma unroll
      for (int n = 0; n < NTW; ++n) {
        int lcol = (cg * NTW + n) * 16 + m;
#pragma unroll
        for (int r = 0; r < 4; ++r)
          acc[n][r] += red[((s - 1) * RG + rowg) * 16 * CoP + (rl + r) * CoP + lcol];
      }
  }

  // epilogue: C/D layout col=lane&15, row=(lane>>4)*4+reg
#pragma unroll
  for (int n = 0; n < NTW; ++n) {
    int col = (ct0 + n) * 16 + m;
    float s_ = sc[col], b_ = bi[col];
#pragma unroll
    for (int r = 0; r < 4; ++r) {
      int orow = i0 + rl + r;
      if (orow < nout)
        out[(size_t)orow * Co + col] = (_Float16)fmaxf(fmaf(acc[n][r], s_, b_), 0.f);
    }
  }
}

// ---- two-stage segment max; batch_out nondecreasing; one atomic per run.
__global__ __launch_bounds__(256) void segmax2(const _Float16* __restrict__ x,
                                               const int* __restrict__ batch,
                                               int n, float* __restrict__ out) {
  const int RPB = 128;
  int c = threadIdx.x & 127, g = threadIdx.x >> 7;
  int r0 = blockIdx.x * RPB + g;
  int rend = min(n, blockIdx.x * RPB + RPB);
  float mx = 0.f;
  int cb = -1;
  for (int r = r0; r < rend; r += 2) {
    int b = batch[r];
    if (b != cb) {
      if (cb >= 0)
        atomicMax((int*)out + ((size_t)cb << 7) + c, __float_as_int(mx));
      cb = b;
      mx = 0.f;
    }
    mx = fmaxf(mx, (float)x[(size_t)r * 128 + c]);
  }
  if (cb >= 0)
    atomicMax((int*)out + ((size_t)cb << 7) + c, __float_as_int(mx));
}

extern "C" void kernel_launch(void* const* d_in, const int* in_sizes, int n_in,
                              void* d_out, int out_size, void* d_ws, size_t ws_size,
                              hipStream_t stream) {
  auto I = [&](int idx) { return (const int*)d_in[idx]; };
  auto F = [&](int idx) { return (const float*)d_in[idx]; };

  const int N0  = in_sizes[1];
  const int R1  = in_sizes[3] / 27;
  const int R2s = in_sizes[5] / 27;
  const int n2  = in_sizes[7];
  const int R2  = in_sizes[8] / 27;
  const int R3s = in_sizes[10] / 27;
  const int n3  = in_sizes[12];
  const int R3  = in_sizes[13] / 27;
  const int R4s = in_sizes[15] / 27;
  const int n4  = in_sizes[17];
  const int R4  = in_sizes[18] / 27;
  const int Ro  = in_sizes[20] / 3;
  const int no  = in_sizes[22];

  const int wIdx[12] = {23, 26, 29, 32, 35, 38, 41, 44, 47, 50, 53, 56};
  const int Ks[12]   = {27, 27, 27, 27, 27, 27, 27, 27, 27, 27, 27, 3};
  const int Cis[12]  = {4, 16, 16, 32, 32, 32, 64, 64, 64, 64, 64, 64};
  const int Cos[12]  = {16, 16, 32, 32, 32, 64, 64, 64, 64, 64, 64, 128};
  WPs P;
  int wtot = 0;
  int bpOff[12];
  for (int l = 0; l < 12; ++l) {
    int cip = Cis[l] < 8 ? 8 : Cis[l];
    int nch = (Ks[l] * cip + 31) / 32;
    int nt = Cos[l] / 16;
    int sz = nch * nt * 512;
    P.d[l].W = F(wIdx[l]);
    P.d[l].K = Ks[l];  P.d[l].Ci = Cis[l];  P.d[l].CiPad = cip;  P.d[l].Co = Cos[l];
    P.d[l].start = wtot;  P.d[l].end = wtot + sz;  P.d[l].off = wtot;
    bpOff[l] = wtot;
    wtot += sz;
  }

  RBs RP;
  const int rbRin[8]  = {3, 5, 8, 10, 13, 15, 18, 20};
  const int rbRs[8]   = {R1, R2s, R2, R3s, R3, R4s, R4, Ro};
  const int rbKs[8]   = {27, 27, 27, 27, 27, 27, 27, 3};
  const int rbNout[8] = {N0, n2, n2, n3, n3, n4, n4, no};
  size_t tblInts[8], tblOff[8];
  size_t totTbl = 0;
  int totFill = 0;
  for (int l = 0; l < 8; ++l) {
    tblInts[l] = (size_t)rbNout[l] * rbKs[l];
    tblOff[l] = totTbl;
    totTbl += tblInts[l];
    RP.d[l].rin = I(rbRin[l]);
    RP.d[l].rout = I(rbRin[l] + 1);
    RP.d[l].K = rbKs[l];  RP.d[l].R = rbRs[l];  RP.d[l].nout = rbNout[l];
    RP.d[l].start = totFill;
    totFill += rbKs[l] * rbRs[l];
    RP.d[l].end = totFill;
    RP.d[l].off = (int)tblOff[l];
  }

  size_t S = (size_t)(N0 + 1) * 16;
  auto smax = [&](size_t v) { if (v > S) S = v; };
  smax((size_t)(n2 + 1) * 32);
  smax((size_t)(n3 + 1) * 64);
  smax((size_t)(n4 + 1) * 64);
  smax((size_t)(no + 1) * 128);
  S = (S + 7) & ~(size_t)7;

  _Float16* h = (_Float16*)d_ws;
  size_t off = 0;
  _Float16* f0 = h + off;   off += (size_t)(N0 + 1) * 8;
  _Float16* bufA = h + off; off += S;
  _Float16* bufB = h + off; off += S;
  _Float16* Bp = h + off;   off += (size_t)((wtot + 7) & ~7);
  int* tblBase = (int*)(h + off);
  size_t usedBytes = off * 2;
  bool prebuilt = (usedBytes + totTbl * 4 <= ws_size);

  feat_kernel<<<cdiv_i((N0 + 1) * 8, 256), 256, 0, stream>>>(F(0), I(1), f0, N0);
  wpack_all<<<cdiv_i(wtot, 256), 256, 0, stream>>>(P, Bp, wtot);
  hipMemsetAsync(d_out, 0, (size_t)out_size * 4, stream);

  const int l2rb[12] = {0, 0, 1, 2, 2, 3, 4, 4, 5, 6, 6, 7};
  const int* tblL[12];
  if (prebuilt) {
    hipMemsetAsync(tblBase, 0xFF, totTbl * 4, stream);
    rb_fill_all<<<cdiv_i(totFill, 256), 256, 0, stream>>>(RP, tblBase, totFill);
    for (int l = 0; l < 12; ++l) tblL[l] = tblBase + tblOff[l2rb[l]];
  } else {
    for (int l = 0; l < 12; ++l) tblL[l] = tblBase;
  }
  auto buildSeq = [&](int rb) {
    if (prebuilt) return;
    hipMemsetAsync(tblBase, 0xFF, tblInts[rb] * 4, stream);
    tbl_fill_kernel<<<cdiv_i(rbKs[rb] * rbRs[rb], 256), 256, 0, stream>>>(
        I(rbRin[rb]), I(rbRin[rb] + 1), tblBase, rbKs[rb], rbRs[rb], rbNout[rb]);
  };

#define CONV(Kk, CIP, CO, KSv, CGv, CBv, IN, LI, OUTB, NOUT, NIN)             \
  do {                                                                        \
    constexpr int rowsPerBlk = (4 / (KSv * CGv)) * 16;                        \
    int nblk = cdiv_i(NOUT, rowsPerBlk) * CBv;                                \
    conv_mfma<Kk, CIP, CO, KSv, CGv, CBv>                                     \
        <<<nblk, 256, 0, stream>>>(                                           \
            IN, Bp + bpOff[LI], tblL[LI], F(wIdx[LI] + 1), F(wIdx[LI] + 2),   \
            OUTB, NOUT, NIN);                                                 \
  } while (0)

  // stage 1
  buildSeq(0);
  CONV(27, 8, 16, 1, 1, 1, f0, 0, bufA, N0, N0);      // conv_in   64 rows
  CONV(27, 16, 16, 2, 1, 1, bufA, 1, bufB, N0, N0);   // conv1     32 rows
  // stage 2
  buildSeq(1);
  CONV(27, 16, 32, 2, 1, 1, bufB, 2, bufA, n2, N0);   // conv2a    32 rows
  buildSeq(2);
  CONV(27, 32, 32, 2, 1, 1, bufA, 3, bufB, n2, n2);   // conv2b    32 rows
  CONV(27, 32, 32, 2, 1, 1, bufB, 4, bufA, n2, n2);   // conv2c
  // stage 3
  buildSeq(3);
  CONV(27, 32, 64, 4, 1, 1, bufA, 5, bufB, n3, n2);   // conv3a    16 rows
  buildSeq(4);
  CONV(27, 64, 64, 4, 1, 1, bufB, 6, bufA, n3, n3);   // conv3b
  CONV(27, 64, 64, 4, 1, 1, bufA, 7, bufB, n3, n3);   // conv3c
  // stage 4 (few rows: also split cols across blocks)
  buildSeq(5);
  CONV(27, 64, 64, 4, 1, 2, bufB, 8, bufA, n4, n3);   // conv4a
  buildSeq(6);
  CONV(27, 64, 64, 4, 1, 2, bufA, 9, bufB, n4, n4);   // conv4b
  CONV(27, 64, 64, 4, 1, 2, bufB, 10, bufA, n4, n4);  // conv4c
  // out conv (K=3, Co=128)
  buildSeq(7);
  CONV(3, 64, 128, 2, 2, 2, bufA, 11, bufB, no, n4);  // conv_out
  segmax2<<<cdiv_i(no, 128), 256, 0, stream>>>(bufB, I(22), no, (float*)d_out);
#undef CONV
}